// Round 4
// baseline (281.761 us; speedup 1.0000x reference)
//
#include <hip/hip_runtime.h>
#include <cstdint>

#define D 256
#define NC 32
#define NCLS 10
#define KNN 10
#define NBLK 32

typedef const __attribute__((address_space(1))) unsigned int* gp1_t;
typedef __attribute__((address_space(3))) unsigned int* sp3_t;

__device__ __forceinline__ float wave_sum(float v) {
  #pragma unroll
  for (int off = 32; off; off >>= 1) v += __shfl_xor(v, off);
  return v;
}

// ---------------- key = x2 - 2*xc ----------------
// 512 rows/block = 2 rowgroups x 256. 4 waves: wave w -> rowgroup w>>1, concepts (w&1)*16..+15.
// Lane owns 4 CONSECUTIVE rows (4*lane..4*lane+3) -> float4 writeback.
// LDS per rg per chunk: 512 float4; slot q=8L+m holds row 4L+((m^(L&7))>>1), half ((m^(L&7))&1).
// C addresses uniform via readfirstlane -> s_load + SGPR-operand v_fma.
__global__ __launch_bounds__(256, 4) void k_key(const float* __restrict__ X,
                                                const float* __restrict__ Cc,
                                                float* __restrict__ keyT, int N) {
  __shared__ float4 xt[2][1024];   // [buf][rg*512 + q], 32 KB
  int t = threadIdx.x;
  int lane = t & 63;
  int l7 = lane & 7;
  int wvu = __builtin_amdgcn_readfirstlane(t >> 6);   // uniform wave id
  int rg = wvu >> 1;
  int cbase = (wvu & 1) * 16;

  auto stage = [&](int buf, int ch) {
    #pragma unroll
    for (int jj = 0; jj < 4; ++jj) {
      int slot = wvu * 256 + jj * 64 + lane;          // linear LDS f4 slot
      int q = slot & 511, rgs = slot >> 9;
      int L = q >> 3, m = q & 7;
      int v = m ^ (L & 7);
      int row = (blockIdx.x << 9) + (rgs << 8) + 4 * L + (v >> 1);
      if (row >= N) row = N - 1;
      const float* src = X + (size_t)row * D + ch * 8 + (v & 1) * 4;
      __builtin_amdgcn_global_load_lds((gp1_t)(const void*)src,
          (sp3_t)(void*)(&xt[buf][wvu * 256 + jj * 64]), 16, 0, 0);
    }
  };

  stage(0, 0);

  float acc[4][16];
  float x2[4];
  #pragma unroll
  for (int j = 0; j < 4; ++j) {
    x2[j] = 0.f;
    #pragma unroll
    for (int c = 0; c < 16; ++c) acc[j][c] = 0.f;
  }

  for (int ch = 0; ch < 32; ++ch) {
    __syncthreads();                       // staged chunk visible; prev reads done
    int cb = ch & 1, nb = cb ^ 1;
    if (ch + 1 < 32) stage(nb, ch + 1);

    float4 xv[4][2];
    #pragma unroll
    for (int j = 0; j < 4; ++j)
      #pragma unroll
      for (int s = 0; s < 2; ++s)
        xv[j][s] = xt[cb][rg * 512 + 8 * lane + ((2 * j + s) ^ l7)];

    #pragma unroll
    for (int s = 0; s < 2; ++s)
      #pragma unroll
      for (int dd = 0; dd < 4; ++dd) {
        const float* cp = Cc + (size_t)((ch * 8 + s * 4 + dd) * NC) + cbase;
        float4 ca = *(const float4*)cp;
        float4 cb4 = *(const float4*)(cp + 4);
        float4 cc4 = *(const float4*)(cp + 8);
        float4 cd4 = *(const float4*)(cp + 12);
        float cv[16] = {ca.x, ca.y, ca.z, ca.w, cb4.x, cb4.y, cb4.z, cb4.w,
                        cc4.x, cc4.y, cc4.z, cc4.w, cd4.x, cd4.y, cd4.z, cd4.w};
        #pragma unroll
        for (int j = 0; j < 4; ++j) {
          float xd = reinterpret_cast<const float*>(&xv[j][s])[dd];
          x2[j] += xd * xd;
          #pragma unroll
          for (int c = 0; c < 16; ++c) acc[j][c] += xd * cv[c];
        }
      }
  }

  int gr = (blockIdx.x << 9) + (rg << 8) + 4 * lane;
  if (gr < N) {    // N%4==0 and gr%4==0 -> full float4 or nothing
    #pragma unroll
    for (int c = 0; c < 16; ++c) {
      float4 v4 = make_float4(x2[0] - 2.f * acc[0][c], x2[1] - 2.f * acc[1][c],
                              x2[2] - 2.f * acc[2][c], x2[3] - 2.f * acc[3][c]);
      *reinterpret_cast<float4*>(keyT + (size_t)(cbase + c) * N + gr) = v4;
    }
  }
}

// ---------------- fused gram + Gauss-Jordan solve + scalar stats ----------------
#define AUGW (NC + NCLS)   // 42
__global__ __launch_bounds__(1024) void k_gramsolve(const float* __restrict__ C,
                                                    const float* __restrict__ W,
                                                    float* __restrict__ S,
                                                    float* __restrict__ out, int bs) {
  __shared__ float Cs[D * NC];     // 32 KB
  __shared__ float Ws[D * NCLS];   // 10 KB
  __shared__ float aug[NC * AUGW];
  int tid = threadIdx.x;
  {
    const float4* C4 = (const float4*)C;  float4* Cs4 = (float4*)Cs;
    Cs4[tid] = C4[tid]; Cs4[tid + 1024] = C4[tid + 1024];
    const float4* W4 = (const float4*)W;  float4* Ws4 = (float4*)Ws;
    if (tid < (D * NCLS) / 4) Ws4[tid] = W4[tid];
  }
  __syncthreads();
  for (int e = tid; e < NC * AUGW; e += 1024) {
    int i = e / AUGW, jj = e % AUGW;
    float acc = 0.f;
    if (jj < NC) {
      for (int d = 0; d < D; ++d) acc += Cs[d * NC + i] * Cs[d * NC + jj];
    } else {
      int cls = jj - NC;
      for (int d = 0; d < D; ++d) acc += Cs[d * NC + i] * Ws[d * NCLS + cls];
    }
    aug[e] = acc;
  }
  __syncthreads();

  if (tid < NC) {
    int lane = tid;
    float row[AUGW];
    #pragma unroll
    for (int c = 0; c < AUGW; ++c) row[c] = aug[lane * AUGW + c];

    float rsum = 0.f;
    #pragma unroll
    for (int c = 0; c < NC; ++c) rsum += row[c];
    float diag = row[lane];
    #pragma unroll
    for (int off = 16; off; off >>= 1) {
      rsum += __shfl_xor(rsum, off);
      diag += __shfl_xor(diag, off);
    }
    if (lane == 0) {
      out[(size_t)2 * bs * NCLS + 1] = (rsum - diag) / (float)(NC * NC); // L_sparse_2
      out[(size_t)2 * bs * NCLS + 2] = diag / (float)(NC * NC);          // norm_metrics
    }

    for (int k = 0; k < NC; ++k) {
      float prow[AUGW];
      #pragma unroll
      for (int c = 0; c < AUGW; ++c) prow[c] = __shfl(row[c], k);
      float pinv = 1.0f / prow[k];
      float f = row[k] * pinv;
      if (lane == k) {
        #pragma unroll
        for (int c = 0; c < AUGW; ++c) row[c] *= pinv;
      } else {
        #pragma unroll
        for (int c = 0; c < AUGW; ++c) row[c] -= f * prow[c];
      }
    }
    #pragma unroll
    for (int c = 0; c < NCLS; ++c) S[lane * NCLS + c] = row[NC + c];
  }
}

// ---------------- predictions: orig_pred and y_pred ----------------
// 32 threads/row, contiguous 8-d slice per thread; 512 blocks x 8 rows.
__global__ __launch_bounds__(256) void k_pred(const float* __restrict__ X,
                                              const float* __restrict__ C,
                                              const float* __restrict__ W,
                                              const float* __restrict__ bvec,
                                              const float* __restrict__ S,
                                              float* __restrict__ out, int bs) {
  int t = threadIdx.x;
  int r = blockIdx.x * 8 + (t >> 5);
  int q = t & 31;
  const float4* x4 = reinterpret_cast<const float4*>(X + (size_t)r * D);
  float4 xa = x4[q * 2], xb = x4[q * 2 + 1];

  float a[NC], o[NCLS];
  #pragma unroll
  for (int c = 0; c < NC; ++c) a[c] = 0.f;
  #pragma unroll
  for (int c = 0; c < NCLS; ++c) o[c] = 0.f;

  #pragma unroll
  for (int i = 0; i < 2; ++i) {
    float4 xv = i ? xb : xa;
    #pragma unroll
    for (int dd = 0; dd < 4; ++dd) {
      int d = q * 8 + i * 4 + dd;
      float xd = reinterpret_cast<const float*>(&xv)[dd];
      const float4* cp = reinterpret_cast<const float4*>(C + (size_t)d * NC);
      #pragma unroll
      for (int g = 0; g < 8; ++g) {
        float4 cg = cp[g];
        a[g * 4 + 0] += xd * cg.x; a[g * 4 + 1] += xd * cg.y;
        a[g * 4 + 2] += xd * cg.z; a[g * 4 + 3] += xd * cg.w;
      }
      const float2* wp = reinterpret_cast<const float2*>(W + (size_t)d * NCLS);
      #pragma unroll
      for (int g = 0; g < 5; ++g) {
        float2 wg = wp[g];
        o[g * 2 + 0] += xd * wg.x; o[g * 2 + 1] += xd * wg.y;
      }
    }
  }
  #pragma unroll
  for (int off = 1; off < 32; off <<= 1) {
    #pragma unroll
    for (int c = 0; c < NC; ++c) a[c] += __shfl_xor(a[c], off);
    #pragma unroll
    for (int c = 0; c < NCLS; ++c) o[c] += __shfl_xor(o[c], off);
  }
  if (q == 0) {
    #pragma unroll
    for (int cls = 0; cls < NCLS; ++cls) {
      float y = bvec[cls];
      #pragma unroll
      for (int c = 0; c < NC; ++c) y += a[c] * S[c * NCLS + cls];
      out[(size_t)r * NCLS + cls] = o[cls] + bvec[cls];
      out[(size_t)bs * NCLS + (size_t)r * NCLS + cls] = y;
    }
  }
}

// ---------------- per-(concept, chunk) exact top-10, float4 scan ----------------
__global__ __launch_bounds__(256) void k_topk(const float* __restrict__ keyT,
                                              float* __restrict__ candK,
                                              int* __restrict__ candI, int N) {
  int j = blockIdx.y, blk = blockIdx.x, tid = threadIdx.x;
  const float* key = keyT + (size_t)j * N;
  int per = (((N + NBLK - 1) / NBLK) + 3) & ~3;
  int lo = blk * per;
  int hi = lo + per; if (hi > N) hi = N;

  float bk[KNN]; int bi[KNN];
  #pragma unroll
  for (int q = 0; q < KNN; ++q) { bk[q] = 3.4e38f; bi[q] = 0x7fffffff; }

  if (lo < N) {
    const float4* key4 = reinterpret_cast<const float4*>(key + lo);
    int n4 = (hi - lo) >> 2;
    for (int i4 = tid; i4 < n4; i4 += 256) {
      float4 v4 = key4[i4];
      #pragma unroll
      for (int c = 0; c < 4; ++c) {
        float v = reinterpret_cast<const float*>(&v4)[c];
        int gi = lo + (i4 << 2) + c;
        if (v < bk[KNN - 1] || (v == bk[KNN - 1] && gi < bi[KNN - 1])) {
          float cv = v; int ci = gi;
          #pragma unroll
          for (int q = 0; q < KNN; ++q) {
            bool take = (cv < bk[q]) || (cv == bk[q] && ci < bi[q]);
            if (take) {
              float tf = bk[q]; bk[q] = cv; cv = tf;
              int ti = bi[q]; bi[q] = ci; ci = ti;
            }
          }
        }
      }
    }
    for (int i = lo + (n4 << 2) + tid; i < hi; i += 256) {
      float v = key[i];
      if (v < bk[KNN - 1] || (v == bk[KNN - 1] && i < bi[KNN - 1])) {
        float cv = v; int ci = i;
        #pragma unroll
        for (int q = 0; q < KNN; ++q) {
          bool take = (cv < bk[q]) || (cv == bk[q] && ci < bi[q]);
          if (take) {
            float tf = bk[q]; bk[q] = cv; cv = tf;
            int ti = bi[q]; bi[q] = ci; ci = ti;
          }
        }
      }
    }
  }

  __shared__ float sk[256 * KNN];
  __shared__ int si[256 * KNN];
  __shared__ float wv_[4]; __shared__ int wi_[4];
  #pragma unroll
  for (int q = 0; q < KNN; ++q) { sk[tid * KNN + q] = bk[q]; si[tid * KNN + q] = bi[q]; }
  __syncthreads();

  int p = 0;
  int lane = tid & 63, wv = tid >> 6;
  for (int rr = 0; rr < KNN; ++rr) {
    float myv = (p < KNN) ? sk[tid * KNN + p] : 3.4e38f;
    int mygi = (p < KNN) ? si[tid * KNN + p] : 0x7fffffff;
    float hv = myv; int hgi = mygi;
    #pragma unroll
    for (int off = 32; off; off >>= 1) {
      float ov = __shfl_xor(hv, off); int oi = __shfl_xor(hgi, off);
      if (ov < hv || (ov == hv && oi < hgi)) { hv = ov; hgi = oi; }
    }
    if (lane == 0) { wv_[wv] = hv; wi_[wv] = hgi; }
    __syncthreads();
    float bv = wv_[0]; int bgi = wi_[0];
    #pragma unroll
    for (int w = 1; w < 4; ++w) {
      if (wv_[w] < bv || (wv_[w] == bv && wi_[w] < bgi)) { bv = wv_[w]; bgi = wi_[w]; }
    }
    if (p < KNN && myv == bv && mygi == bgi) p++;
    if (tid == 0) {
      candK[((size_t)j * NBLK + blk) * KNN + rr] = bv;
      candI[((size_t)j * NBLK + blk) * KNN + rr] = bgi;
    }
    __syncthreads();
  }
}

// ---------------- merge + gather + dot + L_sparse_1 (fused final) ----------------
// 1 block x 1024 threads; wave w handles concepts w and w+16, all in registers.
__global__ __launch_bounds__(1024) void k_fin(const float* __restrict__ candK,
                                              const int* __restrict__ candI,
                                              const float* __restrict__ X,
                                              const float* __restrict__ Cc,
                                              float* __restrict__ out, int bs) {
  int t = threadIdx.x, lane = t & 63;
  int w = __builtin_amdgcn_readfirstlane(t >> 6);   // 0..15
  __shared__ float dsum[NC];
  const int M = NBLK * KNN;   // 320

  #pragma unroll
  for (int half = 0; half < 2; ++half) {
    int j = w + half * 16;
    float mv[5]; int mgi[5];
    #pragma unroll
    for (int i = 0; i < 5; ++i) {
      int e = i * 64 + lane;
      mv[i] = candK[(size_t)j * M + e];
      mgi[i] = candI[(size_t)j * M + e];
    }
    float c0 = Cc[(size_t)(4 * lane + 0) * NC + j];
    float c1 = Cc[(size_t)(4 * lane + 1) * NC + j];
    float c2 = Cc[(size_t)(4 * lane + 2) * NC + j];
    float c3 = Cc[(size_t)(4 * lane + 3) * NC + j];
    float part = 0.f;
    #pragma unroll
    for (int r = 0; r < KNN; ++r) {
      float lv = mv[0]; int lgi = mgi[0];
      #pragma unroll
      for (int i = 1; i < 5; ++i)
        if (mv[i] < lv || (mv[i] == lv && mgi[i] < lgi)) { lv = mv[i]; lgi = mgi[i]; }
      float bv = lv; int bgi = lgi;
      #pragma unroll
      for (int off = 32; off; off >>= 1) {
        float ov = __shfl_xor(bv, off); int ogi = __shfl_xor(bgi, off);
        if (ov < bv || (ov == bv && ogi < bgi)) { bv = ov; bgi = ogi; }
      }
      #pragma unroll
      for (int i = 0; i < 5; ++i)
        if (mv[i] == bv && mgi[i] == bgi) { mv[i] = 3.4e38f; mgi[i] = 0x7fffffff; }
      const float4 xr = *reinterpret_cast<const float4*>(X + (size_t)bgi * D + 4 * lane);
      part += xr.x * c0 + xr.y * c1 + xr.z * c2 + xr.w * c3;
    }
    part = wave_sum(part);
    if (lane == 0) dsum[j] = part;
  }
  __syncthreads();
  if (t == 0) {
    float s = 0.f;
    for (int j = 0; j < NC; ++j) s += dsum[j];
    out[(size_t)2 * bs * NCLS] = s / (float)(NC * KNN);
  }
}

extern "C" void kernel_launch(void* const* d_in, const int* in_sizes, int n_in,
                              void* d_out, int out_size, void* d_ws, size_t ws_size,
                              hipStream_t stream) {
  const float* Xb = (const float*)d_in[0]; // train_embedding [bs][D]
  const float* XN = (const float*)d_in[1]; // train_embeddings [N][D]
  const float* C  = (const float*)d_in[2]; // concept [D][NC]
  const float* W  = (const float*)d_in[3]; // W_hx [D][NCLS]
  const float* bv = (const float*)d_in[4]; // b_hx [NCLS]
  float* out = (float*)d_out;

  int bs = in_sizes[0] / D;   // 4096
  int N  = in_sizes[1] / D;   // 200000

  float* w = (float*)d_ws;
  size_t offKey  = 0;
  size_t offS    = (size_t)NC * N;
  size_t offCK   = offS + NC * NCLS;
  size_t offCI   = offCK + (size_t)NC * NBLK * KNN;

  float* keyT  = w + offKey;
  float* S     = w + offS;
  float* candK = w + offCK;
  int*   candI = (int*)(w + offCI);

  k_key<<<dim3((N + 511) / 512), dim3(256), 0, stream>>>(XN, C, keyT, N);
  k_gramsolve<<<dim3(1), dim3(1024), 0, stream>>>(C, W, S, out, bs);
  k_pred<<<dim3(bs / 8), dim3(256), 0, stream>>>(Xb, C, W, bv, S, out, bs);
  k_topk<<<dim3(NBLK, NC), dim3(256), 0, stream>>>(keyT, candK, candI, N);
  k_fin<<<dim3(1), dim3(1024), 0, stream>>>(candK, candI, XN, C, out, bs);
}

// Round 5
// 247.584 us; speedup vs baseline: 1.1380x; 1.1380x over previous
//
#include <hip/hip_runtime.h>
#include <cstdint>

#define D 256
#define NC 32
#define NCLS 10
#define KNN 10
#define NBLK 32

typedef const __attribute__((address_space(1))) unsigned int* gp1_t;
typedef __attribute__((address_space(3))) unsigned int* sp3_t;

__device__ __forceinline__ float wave_sum(float v) {
  #pragma unroll
  for (int off = 32; off; off >>= 1) v += __shfl_xor(v, off);
  return v;
}

// ---------------- key = x2 - 2*xc ----------------
// 64 rows/block, 4 chunks x 64 floats (256B/row/chunk: whole-cacheline fetch, once).
// 4 waves: wave w -> concepts 8w..8w+7 (uniform via readfirstlane -> s_load C).
// lane == row. LDS f4 slot row*16 + (d4 ^ (row&15)); staged linear with
// inverse-swizzled global source (same involution). 2x16KB dbuf -> 5 blocks/CU.
__global__ __launch_bounds__(256, 4) void k_key(const float* __restrict__ X,
                                                const float* __restrict__ Cc,
                                                float* __restrict__ keyT, int N) {
  __shared__ float4 xt[2][1024];   // 2 x 16 KB
  int t = threadIdx.x;
  int lane = t & 63;
  int wvu = __builtin_amdgcn_readfirstlane(t >> 6);
  int rowbase = blockIdx.x * 64;

  auto stage = [&](int buf, int ch) {
    #pragma unroll
    for (int jj = 0; jj < 4; ++jj) {
      int s = jj * 256 + wvu * 64 + lane;        // linear LDS f4 slot
      int row = s >> 4;
      int c4 = (s & 15) ^ (row & 15);            // inverse swizzle on SOURCE
      int gr = rowbase + row; if (gr >= N) gr = N - 1;
      const float* src = X + (size_t)gr * D + ch * 64 + c4 * 4;
      __builtin_amdgcn_global_load_lds((gp1_t)(const void*)src,
          (sp3_t)(void*)(&xt[buf][jj * 256 + wvu * 64]), 16, 0, 0);
    }
  };

  stage(0, 0);

  float acc[8];
  #pragma unroll
  for (int c = 0; c < 8; ++c) acc[c] = 0.f;
  float x2 = 0.f;

  for (int ch = 0; ch < 4; ++ch) {
    __syncthreads();                  // staged chunk visible; prev readers done
    int cb = ch & 1;
    if (ch + 1 < 4) stage(cb ^ 1, ch + 1);
    #pragma unroll
    for (int d4 = 0; d4 < 16; ++d4) {
      float4 xv = xt[cb][lane * 16 + (d4 ^ (lane & 15))];
      #pragma unroll
      for (int dd = 0; dd < 4; ++dd) {
        const float* cp = Cc + (size_t)((ch * 64 + d4 * 4 + dd) * NC) + wvu * 8;
        float4 ca = *(const float4*)cp;          // uniform -> s_load
        float4 cb4 = *(const float4*)(cp + 4);
        float xd = reinterpret_cast<const float*>(&xv)[dd];
        x2 += xd * xd;
        acc[0] += xd * ca.x;  acc[1] += xd * ca.y;
        acc[2] += xd * ca.z;  acc[3] += xd * ca.w;
        acc[4] += xd * cb4.x; acc[5] += xd * cb4.y;
        acc[6] += xd * cb4.z; acc[7] += xd * cb4.w;
      }
    }
  }

  int gr = rowbase + lane;
  if (gr < N) {
    #pragma unroll
    for (int c = 0; c < 8; ++c)
      keyT[(size_t)(wvu * 8 + c) * N + gr] = fmaf(-2.f, acc[c], x2);
  }
}

// ---------------- fused gram + Gauss-Jordan solve + scalar stats ----------------
#define AUGW (NC + NCLS)   // 42
__global__ __launch_bounds__(1024) void k_gramsolve(const float* __restrict__ C,
                                                    const float* __restrict__ W,
                                                    float* __restrict__ S,
                                                    float* __restrict__ out, int bs) {
  __shared__ float Cs[D * NC];     // 32 KB
  __shared__ float Ws[D * NCLS];   // 10 KB
  __shared__ float aug[NC * AUGW];
  int tid = threadIdx.x;
  {
    const float4* C4 = (const float4*)C;  float4* Cs4 = (float4*)Cs;
    Cs4[tid] = C4[tid]; Cs4[tid + 1024] = C4[tid + 1024];
    const float4* W4 = (const float4*)W;  float4* Ws4 = (float4*)Ws;
    if (tid < (D * NCLS) / 4) Ws4[tid] = W4[tid];
  }
  __syncthreads();
  for (int e = tid; e < NC * AUGW; e += 1024) {
    int i = e / AUGW, jj = e % AUGW;
    float acc = 0.f;
    if (jj < NC) {
      for (int d = 0; d < D; ++d) acc += Cs[d * NC + i] * Cs[d * NC + jj];
    } else {
      int cls = jj - NC;
      for (int d = 0; d < D; ++d) acc += Cs[d * NC + i] * Ws[d * NCLS + cls];
    }
    aug[e] = acc;
  }
  __syncthreads();

  if (tid < NC) {
    int lane = tid;
    float row[AUGW];
    #pragma unroll
    for (int c = 0; c < AUGW; ++c) row[c] = aug[lane * AUGW + c];

    float rsum = 0.f;
    #pragma unroll
    for (int c = 0; c < NC; ++c) rsum += row[c];
    float diag = row[lane];
    #pragma unroll
    for (int off = 16; off; off >>= 1) {
      rsum += __shfl_xor(rsum, off);
      diag += __shfl_xor(diag, off);
    }
    if (lane == 0) {
      out[(size_t)2 * bs * NCLS + 1] = (rsum - diag) / (float)(NC * NC); // L_sparse_2
      out[(size_t)2 * bs * NCLS + 2] = diag / (float)(NC * NC);          // norm_metrics
    }

    for (int k = 0; k < NC; ++k) {
      float prow[AUGW];
      #pragma unroll
      for (int c = 0; c < AUGW; ++c) prow[c] = __shfl(row[c], k);
      float pinv = 1.0f / prow[k];
      float f = row[k] * pinv;
      if (lane == k) {
        #pragma unroll
        for (int c = 0; c < AUGW; ++c) row[c] *= pinv;
      } else {
        #pragma unroll
        for (int c = 0; c < AUGW; ++c) row[c] -= f * prow[c];
      }
    }
    #pragma unroll
    for (int c = 0; c < NCLS; ++c) S[lane * NCLS + c] = row[NC + c];
  }
}

// ---------------- predictions: orig_pred and y_pred ----------------
// C,W staged to LDS once (C f4-swizzled); 32 lanes/row x 8 rows/block.
__global__ __launch_bounds__(256) void k_pred(const float* __restrict__ X,
                                              const float* __restrict__ C,
                                              const float* __restrict__ W,
                                              const float* __restrict__ bvec,
                                              const float* __restrict__ S,
                                              float* __restrict__ out, int bs) {
  __shared__ float4 Cs4[2048];   // 32 KB: Cs4[d*8+u] = C4[d*8 + (u ^ ((d>>3)&7))]
  __shared__ float2 Ws2[1280];   // 10 KB
  int t = threadIdx.x;
  const float4* C4 = (const float4*)C;
  for (int s = t; s < 2048; s += 256)
    Cs4[s] = C4[(s & ~7) | ((s & 7) ^ ((s >> 6) & 7))];
  const float2* W2 = (const float2*)W;
  for (int s = t; s < 1280; s += 256) Ws2[s] = W2[s];
  __syncthreads();

  int r = blockIdx.x * 8 + (t >> 5);
  int q = t & 31;
  const float4* x4 = reinterpret_cast<const float4*>(X + (size_t)r * D);
  float4 xa = x4[q * 2], xb = x4[q * 2 + 1];

  float a[NC], o[NCLS];
  #pragma unroll
  for (int c = 0; c < NC; ++c) a[c] = 0.f;
  #pragma unroll
  for (int c = 0; c < NCLS; ++c) o[c] = 0.f;

  #pragma unroll
  for (int i = 0; i < 8; ++i) {
    int d = q * 8 + i;
    float xd = (i < 4) ? reinterpret_cast<const float*>(&xa)[i]
                       : reinterpret_cast<const float*>(&xb)[i - 4];
    int sw = (d >> 3) & 7;
    #pragma unroll
    for (int c4 = 0; c4 < 8; ++c4) {
      float4 cv = Cs4[d * 8 + (c4 ^ sw)];
      a[c4 * 4 + 0] += xd * cv.x; a[c4 * 4 + 1] += xd * cv.y;
      a[c4 * 4 + 2] += xd * cv.z; a[c4 * 4 + 3] += xd * cv.w;
    }
    #pragma unroll
    for (int j = 0; j < 5; ++j) {
      float2 wv = Ws2[d * 5 + j];
      o[j * 2 + 0] += xd * wv.x; o[j * 2 + 1] += xd * wv.y;
    }
  }
  #pragma unroll
  for (int off = 1; off < 32; off <<= 1) {
    #pragma unroll
    for (int c = 0; c < NC; ++c) a[c] += __shfl_xor(a[c], off);
    #pragma unroll
    for (int c = 0; c < NCLS; ++c) o[c] += __shfl_xor(o[c], off);
  }
  if (q < NCLS) {
    float b = bvec[q];
    out[(size_t)r * NCLS + q] = o[q] + b;
    float y = b;
    #pragma unroll
    for (int c = 0; c < NC; ++c) y += a[c] * S[c * NCLS + q];
    out[(size_t)bs * NCLS + (size_t)r * NCLS + q] = y;
  }
}

// ---------------- per-(concept, chunk) exact top-10, float4 scan ----------------
__global__ __launch_bounds__(256) void k_topk(const float* __restrict__ keyT,
                                              float* __restrict__ candK,
                                              int* __restrict__ candI, int N) {
  int j = blockIdx.y, blk = blockIdx.x, tid = threadIdx.x;
  const float* key = keyT + (size_t)j * N;
  int per = (((N + NBLK - 1) / NBLK) + 3) & ~3;
  int lo = blk * per;
  int hi = lo + per; if (hi > N) hi = N;

  float bk[KNN]; int bi[KNN];
  #pragma unroll
  for (int q = 0; q < KNN; ++q) { bk[q] = 3.4e38f; bi[q] = 0x7fffffff; }

  if (lo < N) {
    const float4* key4 = reinterpret_cast<const float4*>(key + lo);
    int n4 = (hi - lo) >> 2;
    for (int i4 = tid; i4 < n4; i4 += 256) {
      float4 v4 = key4[i4];
      #pragma unroll
      for (int c = 0; c < 4; ++c) {
        float v = reinterpret_cast<const float*>(&v4)[c];
        int gi = lo + (i4 << 2) + c;
        if (v < bk[KNN - 1] || (v == bk[KNN - 1] && gi < bi[KNN - 1])) {
          float cv = v; int ci = gi;
          #pragma unroll
          for (int q = 0; q < KNN; ++q) {
            bool take = (cv < bk[q]) || (cv == bk[q] && ci < bi[q]);
            if (take) {
              float tf = bk[q]; bk[q] = cv; cv = tf;
              int ti = bi[q]; bi[q] = ci; ci = ti;
            }
          }
        }
      }
    }
    for (int i = lo + (n4 << 2) + tid; i < hi; i += 256) {
      float v = key[i];
      if (v < bk[KNN - 1] || (v == bk[KNN - 1] && i < bi[KNN - 1])) {
        float cv = v; int ci = i;
        #pragma unroll
        for (int q = 0; q < KNN; ++q) {
          bool take = (cv < bk[q]) || (cv == bk[q] && ci < bi[q]);
          if (take) {
            float tf = bk[q]; bk[q] = cv; cv = tf;
            int ti = bi[q]; bi[q] = ci; ci = ti;
          }
        }
      }
    }
  }

  __shared__ float sk[256 * KNN];
  __shared__ int si[256 * KNN];
  __shared__ float wv_[4]; __shared__ int wi_[4];
  #pragma unroll
  for (int q = 0; q < KNN; ++q) { sk[tid * KNN + q] = bk[q]; si[tid * KNN + q] = bi[q]; }
  __syncthreads();

  int p = 0;
  int lane = tid & 63, wv = tid >> 6;
  for (int rr = 0; rr < KNN; ++rr) {
    float myv = (p < KNN) ? sk[tid * KNN + p] : 3.4e38f;
    int mygi = (p < KNN) ? si[tid * KNN + p] : 0x7fffffff;
    float hv = myv; int hgi = mygi;
    #pragma unroll
    for (int off = 32; off; off >>= 1) {
      float ov = __shfl_xor(hv, off); int oi = __shfl_xor(hgi, off);
      if (ov < hv || (ov == hv && oi < hgi)) { hv = ov; hgi = oi; }
    }
    if (lane == 0) { wv_[wv] = hv; wi_[wv] = hgi; }
    __syncthreads();
    float bv = wv_[0]; int bgi = wi_[0];
    #pragma unroll
    for (int w = 1; w < 4; ++w) {
      if (wv_[w] < bv || (wv_[w] == bv && wi_[w] < bgi)) { bv = wv_[w]; bgi = wi_[w]; }
    }
    if (p < KNN && myv == bv && mygi == bgi) p++;
    if (tid == 0) {
      candK[((size_t)j * NBLK + blk) * KNN + rr] = bv;
      candI[((size_t)j * NBLK + blk) * KNN + rr] = bgi;
    }
    __syncthreads();
  }
}

// ---------------- merge + gather + dot + L_sparse_1 (fused final) ----------------
// 1 block x 1024 threads; wave w handles concepts w and w+16.
// Selection (dependent) first, then 10 INDEPENDENT gathers (latency-overlapped).
__global__ __launch_bounds__(1024) void k_fin(const float* __restrict__ candK,
                                              const int* __restrict__ candI,
                                              const float* __restrict__ X,
                                              const float* __restrict__ Cc,
                                              float* __restrict__ out, int bs) {
  int t = threadIdx.x, lane = t & 63;
  int w = __builtin_amdgcn_readfirstlane(t >> 6);   // 0..15
  __shared__ float dsum[NC];
  const int M = NBLK * KNN;   // 320

  #pragma unroll
  for (int half = 0; half < 2; ++half) {
    int j = w + half * 16;
    float mv[5]; int mgi[5];
    #pragma unroll
    for (int i = 0; i < 5; ++i) {
      int e = i * 64 + lane;
      mv[i] = candK[(size_t)j * M + e];
      mgi[i] = candI[(size_t)j * M + e];
    }
    // --- selection: 10 dependent argmin rounds, indices only ---
    int idx[KNN];
    #pragma unroll
    for (int r = 0; r < KNN; ++r) {
      float lv = mv[0]; int lgi = mgi[0];
      #pragma unroll
      for (int i = 1; i < 5; ++i)
        if (mv[i] < lv || (mv[i] == lv && mgi[i] < lgi)) { lv = mv[i]; lgi = mgi[i]; }
      float bv = lv; int bgi = lgi;
      #pragma unroll
      for (int off = 32; off; off >>= 1) {
        float ov = __shfl_xor(bv, off); int ogi = __shfl_xor(bgi, off);
        if (ov < bv || (ov == bv && ogi < bgi)) { bv = ov; bgi = ogi; }
      }
      #pragma unroll
      for (int i = 0; i < 5; ++i)
        if (mv[i] == bv && mgi[i] == bgi) { mv[i] = 3.4e38f; mgi[i] = 0x7fffffff; }
      idx[r] = bgi;
    }
    // --- gather: 10 independent f4 loads + dot ---
    float c0 = Cc[(size_t)(4 * lane + 0) * NC + j];
    float c1 = Cc[(size_t)(4 * lane + 1) * NC + j];
    float c2 = Cc[(size_t)(4 * lane + 2) * NC + j];
    float c3 = Cc[(size_t)(4 * lane + 3) * NC + j];
    float part = 0.f;
    #pragma unroll
    for (int r = 0; r < KNN; ++r) {
      const float4 xr = *reinterpret_cast<const float4*>(X + (size_t)idx[r] * D + 4 * lane);
      part += xr.x * c0 + xr.y * c1 + xr.z * c2 + xr.w * c3;
    }
    part = wave_sum(part);
    if (lane == 0) dsum[j] = part;
  }
  __syncthreads();
  if (t == 0) {
    float s = 0.f;
    for (int j = 0; j < NC; ++j) s += dsum[j];
    out[(size_t)2 * bs * NCLS] = s / (float)(NC * KNN);
  }
}

extern "C" void kernel_launch(void* const* d_in, const int* in_sizes, int n_in,
                              void* d_out, int out_size, void* d_ws, size_t ws_size,
                              hipStream_t stream) {
  const float* Xb = (const float*)d_in[0]; // train_embedding [bs][D]
  const float* XN = (const float*)d_in[1]; // train_embeddings [N][D]
  const float* C  = (const float*)d_in[2]; // concept [D][NC]
  const float* W  = (const float*)d_in[3]; // W_hx [D][NCLS]
  const float* bv = (const float*)d_in[4]; // b_hx [NCLS]
  float* out = (float*)d_out;

  int bs = in_sizes[0] / D;   // 4096
  int N  = in_sizes[1] / D;   // 200000

  float* w = (float*)d_ws;
  size_t offKey  = 0;
  size_t offS    = (size_t)NC * N;
  size_t offCK   = offS + NC * NCLS;
  size_t offCI   = offCK + (size_t)NC * NBLK * KNN;

  float* keyT  = w + offKey;
  float* S     = w + offS;
  float* candK = w + offCK;
  int*   candI = (int*)(w + offCI);

  k_key<<<dim3((N + 63) / 64), dim3(256), 0, stream>>>(XN, C, keyT, N);
  k_gramsolve<<<dim3(1), dim3(1024), 0, stream>>>(C, W, S, out, bs);
  k_pred<<<dim3(bs / 8), dim3(256), 0, stream>>>(Xb, C, W, bv, S, out, bs);
  k_topk<<<dim3(NBLK, NC), dim3(256), 0, stream>>>(keyT, candK, candI, N);
  k_fin<<<dim3(1), dim3(1024), 0, stream>>>(candK, candI, XN, C, out, bs);
}

// Round 6
// 226.174 us; speedup vs baseline: 1.2458x; 1.0947x over previous
//
#include <hip/hip_runtime.h>
#include <cstdint>

#define D 256
#define NC 32
#define NCLS 10
#define KNN 10
#define NBLK 32

typedef const __attribute__((address_space(1))) unsigned int* gp1_t;
typedef __attribute__((address_space(3))) unsigned int* sp3_t;

__device__ __forceinline__ float wave_sum(float v) {
  #pragma unroll
  for (int off = 32; off; off >>= 1) v += __shfl_xor(v, off);
  return v;
}

// ---------------- key = x2 - 2*xc ----------------
// 64 rows/block, 8 chunks x 32 floats (128B = 1 full line/row/chunk).
// 4 waves; wave w -> concepts 8w..8w+7. lane == row.
// C pre-staged to LDS in wave-sliced layout CL[wv][g][dd][c'] -> inner-loop C
// reads are wave-uniform ds_read_b128 (broadcast, conflict-free).
// X staged global->LDS dbuf via global_load_lds (vmcnt only, drained at barrier).
// Inner loop touches ONLY ds_read + FMA => in-order counted lgkmcnt, no drains.
__global__ __launch_bounds__(256, 3) void k_key(const float* __restrict__ X,
                                                const float* __restrict__ Cc,
                                                float* __restrict__ keyT, int N) {
  __shared__ float CL[8192];        // 32 KB: CL[wv*2048 + g*32 + dd*8 + c']
  __shared__ float4 xt[2][512];     // 2 x 8 KB: xt[buf][row*8 + (f4 ^ (row&7))]
  int t = threadIdx.x;
  int lane = t & 63;
  int wvu = __builtin_amdgcn_readfirstlane(t >> 6);
  int rowbase = blockIdx.x * 64;

  auto stage = [&](int buf, int ch) {
    #pragma unroll
    for (int j = 0; j < 2; ++j) {
      int slot = j * 256 + wvu * 64 + lane;      // linear LDS f4 slot
      int row = slot >> 3, m = slot & 7;
      int f4 = m ^ (row & 7);                    // inverse swizzle on SOURCE
      int gr = rowbase + row; if (gr >= N) gr = N - 1;
      const float* src = X + (size_t)gr * D + ch * 32 + f4 * 4;
      __builtin_amdgcn_global_load_lds((gp1_t)(const void*)src,
          (sp3_t)(void*)(&xt[buf][j * 256 + wvu * 64]), 16, 0, 0);
    }
  };

  stage(0, 0);   // X chunk 0 in flight while we fill CL

  // stage C -> CL (once). e: wv_=e>>11, g=(e&2047)>>5, q=e&31, dd=q>>3, c'=q&7
  #pragma unroll 4
  for (int i = 0; i < 32; ++i) {
    int e = i * 256 + t;
    int wv_ = e >> 11, rem = e & 2047, g = rem >> 5, q = rem & 31;
    int dd = q >> 3, cp = q & 7;
    CL[e] = Cc[(size_t)(g * 4 + dd) * NC + wv_ * 8 + cp];
  }

  float acc[8];
  #pragma unroll
  for (int c = 0; c < 8; ++c) acc[c] = 0.f;
  float x2 = 0.f;

  for (int ch = 0; ch < 8; ++ch) {
    __syncthreads();                 // staged chunk + CL visible; prev readers done
    int cb = ch & 1;
    if (ch < 7) stage(cb ^ 1, ch + 1);
    #pragma unroll
    for (int d4 = 0; d4 < 8; ++d4) {
      float4 xv = xt[cb][lane * 8 + (d4 ^ (lane & 7))];
      int gbase = wvu * 2048 + (ch * 8 + d4) * 32;
      #pragma unroll
      for (int dd = 0; dd < 4; ++dd) {
        float4 ca = *(const float4*)&CL[gbase + dd * 8];       // uniform -> bcast
        float4 cb4 = *(const float4*)&CL[gbase + dd * 8 + 4];
        float xd = reinterpret_cast<const float*>(&xv)[dd];
        x2 += xd * xd;
        acc[0] += xd * ca.x;  acc[1] += xd * ca.y;
        acc[2] += xd * ca.z;  acc[3] += xd * ca.w;
        acc[4] += xd * cb4.x; acc[5] += xd * cb4.y;
        acc[6] += xd * cb4.z; acc[7] += xd * cb4.w;
      }
    }
  }

  int gr = rowbase + lane;
  if (gr < N) {
    #pragma unroll
    for (int c = 0; c < 8; ++c)
      keyT[(size_t)(wvu * 8 + c) * N + gr] = fmaf(-2.f, acc[c], x2);
  }
}

// ---------------- fused gram + Gauss-Jordan solve + scalar stats ----------------
#define AUGW (NC + NCLS)   // 42
__global__ __launch_bounds__(1024) void k_gramsolve(const float* __restrict__ C,
                                                    const float* __restrict__ W,
                                                    float* __restrict__ S,
                                                    float* __restrict__ out, int bs) {
  __shared__ float Cs[D * NC];     // 32 KB
  __shared__ float Ws[D * NCLS];   // 10 KB
  __shared__ float aug[NC * AUGW];
  int tid = threadIdx.x;
  {
    const float4* C4 = (const float4*)C;  float4* Cs4 = (float4*)Cs;
    Cs4[tid] = C4[tid]; Cs4[tid + 1024] = C4[tid + 1024];
    const float4* W4 = (const float4*)W;  float4* Ws4 = (float4*)Ws;
    if (tid < (D * NCLS) / 4) Ws4[tid] = W4[tid];
  }
  __syncthreads();
  for (int e = tid; e < NC * AUGW; e += 1024) {
    int i = e / AUGW, jj = e % AUGW;
    float acc = 0.f;
    if (jj < NC) {
      for (int d = 0; d < D; ++d) acc += Cs[d * NC + i] * Cs[d * NC + jj];
    } else {
      int cls = jj - NC;
      for (int d = 0; d < D; ++d) acc += Cs[d * NC + i] * Ws[d * NCLS + cls];
    }
    aug[e] = acc;
  }
  __syncthreads();

  if (tid < NC) {
    int lane = tid;
    float row[AUGW];
    #pragma unroll
    for (int c = 0; c < AUGW; ++c) row[c] = aug[lane * AUGW + c];

    float rsum = 0.f;
    #pragma unroll
    for (int c = 0; c < NC; ++c) rsum += row[c];
    float diag = row[lane];
    #pragma unroll
    for (int off = 16; off; off >>= 1) {
      rsum += __shfl_xor(rsum, off);
      diag += __shfl_xor(diag, off);
    }
    if (lane == 0) {
      out[(size_t)2 * bs * NCLS + 1] = (rsum - diag) / (float)(NC * NC); // L_sparse_2
      out[(size_t)2 * bs * NCLS + 2] = diag / (float)(NC * NC);          // norm_metrics
    }

    for (int k = 0; k < NC; ++k) {
      float prow[AUGW];
      #pragma unroll
      for (int c = 0; c < AUGW; ++c) prow[c] = __shfl(row[c], k);
      float pinv = 1.0f / prow[k];
      float f = row[k] * pinv;
      if (lane == k) {
        #pragma unroll
        for (int c = 0; c < AUGW; ++c) row[c] *= pinv;
      } else {
        #pragma unroll
        for (int c = 0; c < AUGW; ++c) row[c] -= f * prow[c];
      }
    }
    #pragma unroll
    for (int c = 0; c < NCLS; ++c) S[lane * NCLS + c] = row[NC + c];
  }
}

// ---------------- predictions: orig_pred and y_pred ----------------
__global__ __launch_bounds__(256) void k_pred(const float* __restrict__ X,
                                              const float* __restrict__ C,
                                              const float* __restrict__ W,
                                              const float* __restrict__ bvec,
                                              const float* __restrict__ S,
                                              float* __restrict__ out, int bs) {
  __shared__ float4 Cs4[2048];   // 32 KB: Cs4[d*8+u] = C4[d*8 + (u ^ ((d>>3)&7))]
  __shared__ float2 Ws2[1280];   // 10 KB
  int t = threadIdx.x;
  const float4* C4 = (const float4*)C;
  for (int s = t; s < 2048; s += 256)
    Cs4[s] = C4[(s & ~7) | ((s & 7) ^ ((s >> 6) & 7))];
  const float2* W2 = (const float2*)W;
  for (int s = t; s < 1280; s += 256) Ws2[s] = W2[s];
  __syncthreads();

  int r = blockIdx.x * 8 + (t >> 5);
  int q = t & 31;
  const float4* x4 = reinterpret_cast<const float4*>(X + (size_t)r * D);
  float4 xa = x4[q * 2], xb = x4[q * 2 + 1];

  float a[NC], o[NCLS];
  #pragma unroll
  for (int c = 0; c < NC; ++c) a[c] = 0.f;
  #pragma unroll
  for (int c = 0; c < NCLS; ++c) o[c] = 0.f;

  #pragma unroll
  for (int i = 0; i < 8; ++i) {
    int d = q * 8 + i;
    float xd = (i < 4) ? reinterpret_cast<const float*>(&xa)[i]
                       : reinterpret_cast<const float*>(&xb)[i - 4];
    int sw = (d >> 3) & 7;
    #pragma unroll
    for (int c4 = 0; c4 < 8; ++c4) {
      float4 cv = Cs4[d * 8 + (c4 ^ sw)];
      a[c4 * 4 + 0] += xd * cv.x; a[c4 * 4 + 1] += xd * cv.y;
      a[c4 * 4 + 2] += xd * cv.z; a[c4 * 4 + 3] += xd * cv.w;
    }
    #pragma unroll
    for (int j = 0; j < 5; ++j) {
      float2 wv = Ws2[d * 5 + j];
      o[j * 2 + 0] += xd * wv.x; o[j * 2 + 1] += xd * wv.y;
    }
  }
  #pragma unroll
  for (int off = 1; off < 32; off <<= 1) {
    #pragma unroll
    for (int c = 0; c < NC; ++c) a[c] += __shfl_xor(a[c], off);
    #pragma unroll
    for (int c = 0; c < NCLS; ++c) o[c] += __shfl_xor(o[c], off);
  }
  if (q < NCLS) {
    float b = bvec[q];
    out[(size_t)r * NCLS + q] = o[q] + b;
    float y = b;
    #pragma unroll
    for (int c = 0; c < NC; ++c) y += a[c] * S[c * NCLS + q];
    out[(size_t)bs * NCLS + (size_t)r * NCLS + q] = y;
  }
}

// ---------------- per-(concept, chunk) exact top-10, float4 scan ----------------
__global__ __launch_bounds__(256) void k_topk(const float* __restrict__ keyT,
                                              float* __restrict__ candK,
                                              int* __restrict__ candI, int N) {
  int j = blockIdx.y, blk = blockIdx.x, tid = threadIdx.x;
  const float* key = keyT + (size_t)j * N;
  int per = (((N + NBLK - 1) / NBLK) + 3) & ~3;
  int lo = blk * per;
  int hi = lo + per; if (hi > N) hi = N;

  float bk[KNN]; int bi[KNN];
  #pragma unroll
  for (int q = 0; q < KNN; ++q) { bk[q] = 3.4e38f; bi[q] = 0x7fffffff; }

  if (lo < N) {
    const float4* key4 = reinterpret_cast<const float4*>(key + lo);
    int n4 = (hi - lo) >> 2;
    for (int i4 = tid; i4 < n4; i4 += 256) {
      float4 v4 = key4[i4];
      #pragma unroll
      for (int c = 0; c < 4; ++c) {
        float v = reinterpret_cast<const float*>(&v4)[c];
        int gi = lo + (i4 << 2) + c;
        if (v < bk[KNN - 1] || (v == bk[KNN - 1] && gi < bi[KNN - 1])) {
          float cv = v; int ci = gi;
          #pragma unroll
          for (int q = 0; q < KNN; ++q) {
            bool take = (cv < bk[q]) || (cv == bk[q] && ci < bi[q]);
            if (take) {
              float tf = bk[q]; bk[q] = cv; cv = tf;
              int ti = bi[q]; bi[q] = ci; ci = ti;
            }
          }
        }
      }
    }
    for (int i = lo + (n4 << 2) + tid; i < hi; i += 256) {
      float v = key[i];
      if (v < bk[KNN - 1] || (v == bk[KNN - 1] && i < bi[KNN - 1])) {
        float cv = v; int ci = i;
        #pragma unroll
        for (int q = 0; q < KNN; ++q) {
          bool take = (cv < bk[q]) || (cv == bk[q] && ci < bi[q]);
          if (take) {
            float tf = bk[q]; bk[q] = cv; cv = tf;
            int ti = bi[q]; bi[q] = ci; ci = ti;
          }
        }
      }
    }
  }

  __shared__ float sk[256 * KNN];
  __shared__ int si[256 * KNN];
  __shared__ float wv_[4]; __shared__ int wi_[4];
  #pragma unroll
  for (int q = 0; q < KNN; ++q) { sk[tid * KNN + q] = bk[q]; si[tid * KNN + q] = bi[q]; }
  __syncthreads();

  int p = 0;
  int lane = tid & 63, wv = tid >> 6;
  for (int rr = 0; rr < KNN; ++rr) {
    float myv = (p < KNN) ? sk[tid * KNN + p] : 3.4e38f;
    int mygi = (p < KNN) ? si[tid * KNN + p] : 0x7fffffff;
    float hv = myv; int hgi = mygi;
    #pragma unroll
    for (int off = 32; off; off >>= 1) {
      float ov = __shfl_xor(hv, off); int oi = __shfl_xor(hgi, off);
      if (ov < hv || (ov == hv && oi < hgi)) { hv = ov; hgi = oi; }
    }
    if (lane == 0) { wv_[wv] = hv; wi_[wv] = hgi; }
    __syncthreads();
    float bv = wv_[0]; int bgi = wi_[0];
    #pragma unroll
    for (int w = 1; w < 4; ++w) {
      if (wv_[w] < bv || (wv_[w] == bv && wi_[w] < bgi)) { bv = wv_[w]; bgi = wi_[w]; }
    }
    if (p < KNN && myv == bv && mygi == bgi) p++;
    if (tid == 0) {
      candK[((size_t)j * NBLK + blk) * KNN + rr] = bv;
      candI[((size_t)j * NBLK + blk) * KNN + rr] = bgi;
    }
    __syncthreads();
  }
}

// ---------------- merge + gather + dot + L_sparse_1 (fused final) ----------------
__global__ __launch_bounds__(1024) void k_fin(const float* __restrict__ candK,
                                              const int* __restrict__ candI,
                                              const float* __restrict__ X,
                                              const float* __restrict__ Cc,
                                              float* __restrict__ out, int bs) {
  int t = threadIdx.x, lane = t & 63;
  int w = __builtin_amdgcn_readfirstlane(t >> 6);   // 0..15
  __shared__ float dsum[NC];
  const int M = NBLK * KNN;   // 320

  #pragma unroll
  for (int half = 0; half < 2; ++half) {
    int j = w + half * 16;
    float mv[5]; int mgi[5];
    #pragma unroll
    for (int i = 0; i < 5; ++i) {
      int e = i * 64 + lane;
      mv[i] = candK[(size_t)j * M + e];
      mgi[i] = candI[(size_t)j * M + e];
    }
    int idx[KNN];
    #pragma unroll
    for (int r = 0; r < KNN; ++r) {
      float lv = mv[0]; int lgi = mgi[0];
      #pragma unroll
      for (int i = 1; i < 5; ++i)
        if (mv[i] < lv || (mv[i] == lv && mgi[i] < lgi)) { lv = mv[i]; lgi = mgi[i]; }
      float bv = lv; int bgi = lgi;
      #pragma unroll
      for (int off = 32; off; off >>= 1) {
        float ov = __shfl_xor(bv, off); int ogi = __shfl_xor(bgi, off);
        if (ov < bv || (ov == bv && ogi < bgi)) { bv = ov; bgi = ogi; }
      }
      #pragma unroll
      for (int i = 0; i < 5; ++i)
        if (mv[i] == bv && mgi[i] == bgi) { mv[i] = 3.4e38f; mgi[i] = 0x7fffffff; }
      idx[r] = bgi;
    }
    float c0 = Cc[(size_t)(4 * lane + 0) * NC + j];
    float c1 = Cc[(size_t)(4 * lane + 1) * NC + j];
    float c2 = Cc[(size_t)(4 * lane + 2) * NC + j];
    float c3 = Cc[(size_t)(4 * lane + 3) * NC + j];
    float part = 0.f;
    #pragma unroll
    for (int r = 0; r < KNN; ++r) {
      const float4 xr = *reinterpret_cast<const float4*>(X + (size_t)idx[r] * D + 4 * lane);
      part += xr.x * c0 + xr.y * c1 + xr.z * c2 + xr.w * c3;
    }
    part = wave_sum(part);
    if (lane == 0) dsum[j] = part;
  }
  __syncthreads();
  if (t == 0) {
    float s = 0.f;
    for (int j = 0; j < NC; ++j) s += dsum[j];
    out[(size_t)2 * bs * NCLS] = s / (float)(NC * KNN);
  }
}

extern "C" void kernel_launch(void* const* d_in, const int* in_sizes, int n_in,
                              void* d_out, int out_size, void* d_ws, size_t ws_size,
                              hipStream_t stream) {
  const float* Xb = (const float*)d_in[0]; // train_embedding [bs][D]
  const float* XN = (const float*)d_in[1]; // train_embeddings [N][D]
  const float* C  = (const float*)d_in[2]; // concept [D][NC]
  const float* W  = (const float*)d_in[3]; // W_hx [D][NCLS]
  const float* bv = (const float*)d_in[4]; // b_hx [NCLS]
  float* out = (float*)d_out;

  int bs = in_sizes[0] / D;   // 4096
  int N  = in_sizes[1] / D;   // 200000

  float* w = (float*)d_ws;
  size_t offKey  = 0;
  size_t offS    = (size_t)NC * N;
  size_t offCK   = offS + NC * NCLS;
  size_t offCI   = offCK + (size_t)NC * NBLK * KNN;

  float* keyT  = w + offKey;
  float* S     = w + offS;
  float* candK = w + offCK;
  int*   candI = (int*)(w + offCI);

  k_key<<<dim3((N + 63) / 64), dim3(256), 0, stream>>>(XN, C, keyT, N);
  k_gramsolve<<<dim3(1), dim3(1024), 0, stream>>>(C, W, S, out, bs);
  k_pred<<<dim3(bs / 8), dim3(256), 0, stream>>>(Xb, C, W, bv, S, out, bs);
  k_topk<<<dim3(NBLK, NC), dim3(256), 0, stream>>>(keyT, candK, candI, N);
  k_fin<<<dim3(1), dim3(1024), 0, stream>>>(candK, candI, XN, C, out, bs);
}

// Round 7
// 223.339 us; speedup vs baseline: 1.2616x; 1.0127x over previous
//
#include <hip/hip_runtime.h>
#include <cstdint>

#define D 256
#define NC 32
#define NCLS 10
#define KNN 10
#define NBLK 32

typedef const __attribute__((address_space(1))) unsigned int* gp1_t;
typedef __attribute__((address_space(3))) unsigned int* sp3_t;

__device__ __forceinline__ float wave_sum(float v) {
  #pragma unroll
  for (int off = 32; off; off >>= 1) v += __shfl_xor(v, off);
  return v;
}

// ---------------- key = x2 - 2*xc ----------------
// 256 rows/block, 128 threads (2 waves). Wave w -> concepts 16w..16w+15.
// Lane owns 4 rows {l, l+64, l+128, l+192}; acc 4x16.
// 16 chunks x 16 floats. X swizzled f4 slot: R*4 + (d4 ^ ((R>>1)&3)) -> 8/bank min.
// C chunk-staged to LDS (2KB dbuf) -> inner loop = ds_read + FMA only.
// Per d4: 4 x-reads + 16 uniform C-reads feed 272 FMA -> VALU-bound.
__global__ __launch_bounds__(128, 2) void k_key(const float* __restrict__ X,
                                                const float* __restrict__ Cc,
                                                float* __restrict__ keyT, int N) {
  __shared__ float4 xt[2][1024];   // 2 x 16 KB
  __shared__ float cl[2][512];     // 2 x 2 KB
  int t = threadIdx.x;
  int lane = t & 63;
  int wvu = __builtin_amdgcn_readfirstlane(t >> 6);   // 0 or 1
  int rowbase = blockIdx.x * 256;
  int sw = (lane >> 1) & 3;                           // x-read swizzle (lane-only)

  auto stage = [&](int buf, int ch) {
    // X: 256 rows x 16 floats = 1024 f4 slots; slot s: R=s>>2, m=s&3, f4=m^((R>>1)&3)
    #pragma unroll
    for (int i = 0; i < 8; ++i) {
      int sbase = i * 128 + wvu * 64;
      int s = sbase + lane;
      int R = s >> 2, m = s & 3;
      int f4 = m ^ ((R >> 1) & 3);
      int gr = rowbase + R; if (gr >= N) gr = N - 1;
      const float* src = X + (size_t)gr * D + ch * 16 + f4 * 4;
      __builtin_amdgcn_global_load_lds((gp1_t)(const void*)src,
          (sp3_t)(void*)(&xt[buf][sbase]), 16, 0, 0);
    }
    // C chunk: 16 d x 32 c = 512 floats = 128 f4 slots, linear
    {
      int sbase = wvu * 64;
      int s = sbase + lane;
      const float* src = Cc + (size_t)ch * 16 * NC + (size_t)s * 4;
      __builtin_amdgcn_global_load_lds((gp1_t)(const void*)src,
          (sp3_t)(void*)(&cl[buf][sbase * 4]), 16, 0, 0);
    }
  };

  stage(0, 0);

  float acc[4][16];
  float x2[4];
  #pragma unroll
  for (int j = 0; j < 4; ++j) {
    x2[j] = 0.f;
    #pragma unroll
    for (int c = 0; c < 16; ++c) acc[j][c] = 0.f;
  }

  for (int ch = 0; ch < 16; ++ch) {
    __syncthreads();               // staged chunk visible; prev readers done
    int cb = ch & 1;
    if (ch < 15) stage(cb ^ 1, ch + 1);
    #pragma unroll
    for (int d4 = 0; d4 < 4; ++d4) {
      float4 xv[4];
      #pragma unroll
      for (int j = 0; j < 4; ++j)
        xv[j] = xt[cb][(j * 64 + lane) * 4 + (d4 ^ sw)];
      #pragma unroll
      for (int dd = 0; dd < 4; ++dd) {
        const float4* cp = (const float4*)&cl[cb][(d4 * 4 + dd) * NC + wvu * 16];
        float4 c0 = cp[0], c1 = cp[1], c2 = cp[2], c3 = cp[3];   // uniform -> bcast
        #pragma unroll
        for (int j = 0; j < 4; ++j) {
          float xd = reinterpret_cast<const float*>(&xv[j])[dd];
          x2[j] += xd * xd;
          acc[j][0]  += xd * c0.x;  acc[j][1]  += xd * c0.y;
          acc[j][2]  += xd * c0.z;  acc[j][3]  += xd * c0.w;
          acc[j][4]  += xd * c1.x;  acc[j][5]  += xd * c1.y;
          acc[j][6]  += xd * c1.z;  acc[j][7]  += xd * c1.w;
          acc[j][8]  += xd * c2.x;  acc[j][9]  += xd * c2.y;
          acc[j][10] += xd * c2.z;  acc[j][11] += xd * c2.w;
          acc[j][12] += xd * c3.x;  acc[j][13] += xd * c3.y;
          acc[j][14] += xd * c3.z;  acc[j][15] += xd * c3.w;
        }
      }
    }
  }

  #pragma unroll
  for (int j = 0; j < 4; ++j) {
    int gr = rowbase + j * 64 + lane;
    if (gr < N) {
      #pragma unroll
      for (int c = 0; c < 16; ++c)
        keyT[(size_t)(wvu * 16 + c) * N + gr] = fmaf(-2.f, acc[j][c], x2[j]);
    }
  }
}

// ---------------- fused gram + Gauss-Jordan solve + scalar stats ----------------
#define AUGW (NC + NCLS)   // 42
__global__ __launch_bounds__(1024) void k_gramsolve(const float* __restrict__ C,
                                                    const float* __restrict__ W,
                                                    float* __restrict__ S,
                                                    float* __restrict__ out, int bs) {
  __shared__ float Cs[D * NC];     // 32 KB
  __shared__ float Ws[D * NCLS];   // 10 KB
  __shared__ float aug[NC * AUGW];
  int tid = threadIdx.x;
  {
    const float4* C4 = (const float4*)C;  float4* Cs4 = (float4*)Cs;
    Cs4[tid] = C4[tid]; Cs4[tid + 1024] = C4[tid + 1024];
    const float4* W4 = (const float4*)W;  float4* Ws4 = (float4*)Ws;
    if (tid < (D * NCLS) / 4) Ws4[tid] = W4[tid];
  }
  __syncthreads();
  for (int e = tid; e < NC * AUGW; e += 1024) {
    int i = e / AUGW, jj = e % AUGW;
    float acc = 0.f;
    if (jj < NC) {
      for (int d = 0; d < D; ++d) acc += Cs[d * NC + i] * Cs[d * NC + jj];
    } else {
      int cls = jj - NC;
      for (int d = 0; d < D; ++d) acc += Cs[d * NC + i] * Ws[d * NCLS + cls];
    }
    aug[e] = acc;
  }
  __syncthreads();

  if (tid < NC) {
    int lane = tid;
    float row[AUGW];
    #pragma unroll
    for (int c = 0; c < AUGW; ++c) row[c] = aug[lane * AUGW + c];

    float rsum = 0.f;
    #pragma unroll
    for (int c = 0; c < NC; ++c) rsum += row[c];
    float diag = row[lane];
    #pragma unroll
    for (int off = 16; off; off >>= 1) {
      rsum += __shfl_xor(rsum, off);
      diag += __shfl_xor(diag, off);
    }
    if (lane == 0) {
      out[(size_t)2 * bs * NCLS + 1] = (rsum - diag) / (float)(NC * NC); // L_sparse_2
      out[(size_t)2 * bs * NCLS + 2] = diag / (float)(NC * NC);          // norm_metrics
    }

    for (int k = 0; k < NC; ++k) {
      float prow[AUGW];
      #pragma unroll
      for (int c = 0; c < AUGW; ++c) prow[c] = __shfl(row[c], k);
      float pinv = 1.0f / prow[k];
      float f = row[k] * pinv;
      if (lane == k) {
        #pragma unroll
        for (int c = 0; c < AUGW; ++c) row[c] *= pinv;
      } else {
        #pragma unroll
        for (int c = 0; c < AUGW; ++c) row[c] -= f * prow[c];
      }
    }
    #pragma unroll
    for (int c = 0; c < NCLS; ++c) S[lane * NCLS + c] = row[NC + c];
  }
}

// ---------------- predictions: orig_pred and y_pred ----------------
__global__ __launch_bounds__(256) void k_pred(const float* __restrict__ X,
                                              const float* __restrict__ C,
                                              const float* __restrict__ W,
                                              const float* __restrict__ bvec,
                                              const float* __restrict__ S,
                                              float* __restrict__ out, int bs) {
  __shared__ float4 Cs4[2048];   // 32 KB: Cs4[d*8+u] = C4[d*8 + (u ^ ((d>>3)&7))]
  __shared__ float2 Ws2[1280];   // 10 KB
  int t = threadIdx.x;
  const float4* C4 = (const float4*)C;
  for (int s = t; s < 2048; s += 256)
    Cs4[s] = C4[(s & ~7) | ((s & 7) ^ ((s >> 6) & 7))];
  const float2* W2 = (const float2*)W;
  for (int s = t; s < 1280; s += 256) Ws2[s] = W2[s];
  __syncthreads();

  int r = blockIdx.x * 8 + (t >> 5);
  int q = t & 31;
  const float4* x4 = reinterpret_cast<const float4*>(X + (size_t)r * D);
  float4 xa = x4[q * 2], xb = x4[q * 2 + 1];

  float a[NC], o[NCLS];
  #pragma unroll
  for (int c = 0; c < NC; ++c) a[c] = 0.f;
  #pragma unroll
  for (int c = 0; c < NCLS; ++c) o[c] = 0.f;

  #pragma unroll
  for (int i = 0; i < 8; ++i) {
    int d = q * 8 + i;
    float xd = (i < 4) ? reinterpret_cast<const float*>(&xa)[i]
                       : reinterpret_cast<const float*>(&xb)[i - 4];
    int sw = (d >> 3) & 7;
    #pragma unroll
    for (int c4 = 0; c4 < 8; ++c4) {
      float4 cv = Cs4[d * 8 + (c4 ^ sw)];
      a[c4 * 4 + 0] += xd * cv.x; a[c4 * 4 + 1] += xd * cv.y;
      a[c4 * 4 + 2] += xd * cv.z; a[c4 * 4 + 3] += xd * cv.w;
    }
    #pragma unroll
    for (int j = 0; j < 5; ++j) {
      float2 wv = Ws2[d * 5 + j];
      o[j * 2 + 0] += xd * wv.x; o[j * 2 + 1] += xd * wv.y;
    }
  }
  #pragma unroll
  for (int off = 1; off < 32; off <<= 1) {
    #pragma unroll
    for (int c = 0; c < NC; ++c) a[c] += __shfl_xor(a[c], off);
    #pragma unroll
    for (int c = 0; c < NCLS; ++c) o[c] += __shfl_xor(o[c], off);
  }
  if (q < NCLS) {
    float b = bvec[q];
    out[(size_t)r * NCLS + q] = o[q] + b;
    float y = b;
    #pragma unroll
    for (int c = 0; c < NC; ++c) y += a[c] * S[c * NCLS + q];
    out[(size_t)bs * NCLS + (size_t)r * NCLS + q] = y;
  }
}

// ---------------- per-(concept, chunk) exact top-10, float4 scan ----------------
__global__ __launch_bounds__(256) void k_topk(const float* __restrict__ keyT,
                                              float* __restrict__ candK,
                                              int* __restrict__ candI, int N) {
  int j = blockIdx.y, blk = blockIdx.x, tid = threadIdx.x;
  const float* key = keyT + (size_t)j * N;
  int per = (((N + NBLK - 1) / NBLK) + 3) & ~3;
  int lo = blk * per;
  int hi = lo + per; if (hi > N) hi = N;

  float bk[KNN]; int bi[KNN];
  #pragma unroll
  for (int q = 0; q < KNN; ++q) { bk[q] = 3.4e38f; bi[q] = 0x7fffffff; }

  if (lo < N) {
    const float4* key4 = reinterpret_cast<const float4*>(key + lo);
    int n4 = (hi - lo) >> 2;
    for (int i4 = tid; i4 < n4; i4 += 256) {
      float4 v4 = key4[i4];
      #pragma unroll
      for (int c = 0; c < 4; ++c) {
        float v = reinterpret_cast<const float*>(&v4)[c];
        int gi = lo + (i4 << 2) + c;
        if (v < bk[KNN - 1] || (v == bk[KNN - 1] && gi < bi[KNN - 1])) {
          float cv = v; int ci = gi;
          #pragma unroll
          for (int q = 0; q < KNN; ++q) {
            bool take = (cv < bk[q]) || (cv == bk[q] && ci < bi[q]);
            if (take) {
              float tf = bk[q]; bk[q] = cv; cv = tf;
              int ti = bi[q]; bi[q] = ci; ci = ti;
            }
          }
        }
      }
    }
    for (int i = lo + (n4 << 2) + tid; i < hi; i += 256) {
      float v = key[i];
      if (v < bk[KNN - 1] || (v == bk[KNN - 1] && i < bi[KNN - 1])) {
        float cv = v; int ci = i;
        #pragma unroll
        for (int q = 0; q < KNN; ++q) {
          bool take = (cv < bk[q]) || (cv == bk[q] && ci < bi[q]);
          if (take) {
            float tf = bk[q]; bk[q] = cv; cv = tf;
            int ti = bi[q]; bi[q] = ci; ci = ti;
          }
        }
      }
    }
  }

  __shared__ float sk[256 * KNN];
  __shared__ int si[256 * KNN];
  __shared__ float wv_[4]; __shared__ int wi_[4];
  #pragma unroll
  for (int q = 0; q < KNN; ++q) { sk[tid * KNN + q] = bk[q]; si[tid * KNN + q] = bi[q]; }
  __syncthreads();

  int p = 0;
  int lane = tid & 63, wv = tid >> 6;
  for (int rr = 0; rr < KNN; ++rr) {
    float myv = (p < KNN) ? sk[tid * KNN + p] : 3.4e38f;
    int mygi = (p < KNN) ? si[tid * KNN + p] : 0x7fffffff;
    float hv = myv; int hgi = mygi;
    #pragma unroll
    for (int off = 32; off; off >>= 1) {
      float ov = __shfl_xor(hv, off); int oi = __shfl_xor(hgi, off);
      if (ov < hv || (ov == hv && oi < hgi)) { hv = ov; hgi = oi; }
    }
    if (lane == 0) { wv_[wv] = hv; wi_[wv] = hgi; }
    __syncthreads();
    float bv = wv_[0]; int bgi = wi_[0];
    #pragma unroll
    for (int w = 1; w < 4; ++w) {
      if (wv_[w] < bv || (wv_[w] == bv && wi_[w] < bgi)) { bv = wv_[w]; bgi = wi_[w]; }
    }
    if (p < KNN && myv == bv && mygi == bgi) p++;
    if (tid == 0) {
      candK[((size_t)j * NBLK + blk) * KNN + rr] = bv;
      candI[((size_t)j * NBLK + blk) * KNN + rr] = bgi;
    }
    __syncthreads();
  }
}

// ---------------- merge + gather + dot + L_sparse_1 (fused final) ----------------
__global__ __launch_bounds__(1024) void k_fin(const float* __restrict__ candK,
                                              const int* __restrict__ candI,
                                              const float* __restrict__ X,
                                              const float* __restrict__ Cc,
                                              float* __restrict__ out, int bs) {
  int t = threadIdx.x, lane = t & 63;
  int w = __builtin_amdgcn_readfirstlane(t >> 6);   // 0..15
  __shared__ float dsum[NC];
  const int M = NBLK * KNN;   // 320

  #pragma unroll
  for (int half = 0; half < 2; ++half) {
    int j = w + half * 16;
    float mv[5]; int mgi[5];
    #pragma unroll
    for (int i = 0; i < 5; ++i) {
      int e = i * 64 + lane;
      mv[i] = candK[(size_t)j * M + e];
      mgi[i] = candI[(size_t)j * M + e];
    }
    int idx[KNN];
    #pragma unroll
    for (int r = 0; r < KNN; ++r) {
      float lv = mv[0]; int lgi = mgi[0];
      #pragma unroll
      for (int i = 1; i < 5; ++i)
        if (mv[i] < lv || (mv[i] == lv && mgi[i] < lgi)) { lv = mv[i]; lgi = mgi[i]; }
      float bv = lv; int bgi = lgi;
      #pragma unroll
      for (int off = 32; off; off >>= 1) {
        float ov = __shfl_xor(bv, off); int ogi = __shfl_xor(bgi, off);
        if (ov < bv || (ov == bv && ogi < bgi)) { bv = ov; bgi = ogi; }
      }
      #pragma unroll
      for (int i = 0; i < 5; ++i)
        if (mv[i] == bv && mgi[i] == bgi) { mv[i] = 3.4e38f; mgi[i] = 0x7fffffff; }
      idx[r] = bgi;
    }
    float c0 = Cc[(size_t)(4 * lane + 0) * NC + j];
    float c1 = Cc[(size_t)(4 * lane + 1) * NC + j];
    float c2 = Cc[(size_t)(4 * lane + 2) * NC + j];
    float c3 = Cc[(size_t)(4 * lane + 3) * NC + j];
    float part = 0.f;
    #pragma unroll
    for (int r = 0; r < KNN; ++r) {
      const float4 xr = *reinterpret_cast<const float4*>(X + (size_t)idx[r] * D + 4 * lane);
      part += xr.x * c0 + xr.y * c1 + xr.z * c2 + xr.w * c3;
    }
    part = wave_sum(part);
    if (lane == 0) dsum[j] = part;
  }
  __syncthreads();
  if (t == 0) {
    float s = 0.f;
    for (int j = 0; j < NC; ++j) s += dsum[j];
    out[(size_t)2 * bs * NCLS] = s / (float)(NC * KNN);
  }
}

extern "C" void kernel_launch(void* const* d_in, const int* in_sizes, int n_in,
                              void* d_out, int out_size, void* d_ws, size_t ws_size,
                              hipStream_t stream) {
  const float* Xb = (const float*)d_in[0]; // train_embedding [bs][D]
  const float* XN = (const float*)d_in[1]; // train_embeddings [N][D]
  const float* C  = (const float*)d_in[2]; // concept [D][NC]
  const float* W  = (const float*)d_in[3]; // W_hx [D][NCLS]
  const float* bv = (const float*)d_in[4]; // b_hx [NCLS]
  float* out = (float*)d_out;

  int bs = in_sizes[0] / D;   // 4096
  int N  = in_sizes[1] / D;   // 200000

  float* w = (float*)d_ws;
  size_t offKey  = 0;
  size_t offS    = (size_t)NC * N;
  size_t offCK   = offS + NC * NCLS;
  size_t offCI   = offCK + (size_t)NC * NBLK * KNN;

  float* keyT  = w + offKey;
  float* S     = w + offS;
  float* candK = w + offCK;
  int*   candI = (int*)(w + offCI);

  k_key<<<dim3((N + 255) / 256), dim3(128), 0, stream>>>(XN, C, keyT, N);
  k_gramsolve<<<dim3(1), dim3(1024), 0, stream>>>(C, W, S, out, bs);
  k_pred<<<dim3(bs / 8), dim3(256), 0, stream>>>(Xb, C, W, bv, S, out, bs);
  k_topk<<<dim3(NBLK, NC), dim3(256), 0, stream>>>(keyT, candK, candI, N);
  k_fin<<<dim3(1), dim3(1024), 0, stream>>>(candK, candI, XN, C, out, bs);
}

// Round 8
// 198.293 us; speedup vs baseline: 1.4209x; 1.1263x over previous
//
#include <hip/hip_runtime.h>
#include <cstdint>

#define D 256
#define NC 32
#define NCLS 10
#define KNN 10
#define NBLK 32

__device__ __forceinline__ float wave_sum(float v) {
  #pragma unroll
  for (int off = 32; off; off >>= 1) v += __shfl_xor(v, off);
  return v;
}

// ---------------- key = x2 - 2*xc : pure-register, no LDS ----------------
// lane == row (64-thread blocks, 3125 blocks). Per 32-d chunk: 8 float4 loads
// of own row (one 128B line, MSHR-merged), then 32d x 33 FMA with C read at
// wave-uniform affine addresses -> s_load (SMEM pipe). No LDS, no barriers.
__global__ __launch_bounds__(64) void k_key(const float* __restrict__ X,
                                            const float* __restrict__ Cc,
                                            float* __restrict__ keyT, int N) {
  int lane = threadIdx.x;
  int row = blockIdx.x * 64 + lane;
  int rowc = row < N ? row : N - 1;
  const float4* xp = reinterpret_cast<const float4*>(X + (size_t)rowc * D);

  float acc[NC];
  #pragma unroll
  for (int c = 0; c < NC; ++c) acc[c] = 0.f;
  float x2 = 0.f;

  for (int ch = 0; ch < 8; ++ch) {          // 8 chunks x 32 d
    float4 xr[8];
    #pragma unroll
    for (int i = 0; i < 8; ++i) xr[i] = xp[ch * 8 + i];
    #pragma unroll
    for (int i = 0; i < 8; ++i) {
      #pragma unroll
      for (int dd = 0; dd < 4; ++dd) {
        int d = ch * 32 + i * 4 + dd;
        float xd = reinterpret_cast<const float*>(&xr[i])[dd];
        x2 += xd * xd;
        const float* crow = Cc + (size_t)d * NC;   // uniform -> s_load
        #pragma unroll
        for (int c = 0; c < NC; ++c) acc[c] += xd * crow[c];
      }
    }
  }

  if (row < N) {
    #pragma unroll
    for (int c = 0; c < NC; ++c)
      keyT[(size_t)c * N + row] = fmaf(-2.f, acc[c], x2);   // coalesced per c
  }
}

// ---------------- fused gram + Gauss-Jordan solve + scalar stats ----------------
#define AUGW (NC + NCLS)   // 42
__global__ __launch_bounds__(1024) void k_gramsolve(const float* __restrict__ C,
                                                    const float* __restrict__ W,
                                                    float* __restrict__ S,
                                                    float* __restrict__ out, int bs) {
  __shared__ float Cs[D * NC];     // 32 KB
  __shared__ float Ws[D * NCLS];   // 10 KB
  __shared__ float aug[NC * AUGW];
  int tid = threadIdx.x;
  {
    const float4* C4 = (const float4*)C;  float4* Cs4 = (float4*)Cs;
    Cs4[tid] = C4[tid]; Cs4[tid + 1024] = C4[tid + 1024];
    const float4* W4 = (const float4*)W;  float4* Ws4 = (float4*)Ws;
    if (tid < (D * NCLS) / 4) Ws4[tid] = W4[tid];
  }
  __syncthreads();
  for (int e = tid; e < NC * AUGW; e += 1024) {
    int i = e / AUGW, jj = e % AUGW;
    float acc = 0.f;
    if (jj < NC) {
      for (int d = 0; d < D; ++d) acc += Cs[d * NC + i] * Cs[d * NC + jj];
    } else {
      int cls = jj - NC;
      for (int d = 0; d < D; ++d) acc += Cs[d * NC + i] * Ws[d * NCLS + cls];
    }
    aug[e] = acc;
  }
  __syncthreads();

  if (tid < NC) {
    int lane = tid;
    float row[AUGW];
    #pragma unroll
    for (int c = 0; c < AUGW; ++c) row[c] = aug[lane * AUGW + c];

    float rsum = 0.f;
    #pragma unroll
    for (int c = 0; c < NC; ++c) rsum += row[c];
    float diag = row[lane];
    #pragma unroll
    for (int off = 16; off; off >>= 1) {
      rsum += __shfl_xor(rsum, off);
      diag += __shfl_xor(diag, off);
    }
    if (lane == 0) {
      out[(size_t)2 * bs * NCLS + 1] = (rsum - diag) / (float)(NC * NC); // L_sparse_2
      out[(size_t)2 * bs * NCLS + 2] = diag / (float)(NC * NC);          // norm_metrics
    }

    for (int k = 0; k < NC; ++k) {
      float prow[AUGW];
      #pragma unroll
      for (int c = 0; c < AUGW; ++c) prow[c] = __shfl(row[c], k);
      float pinv = 1.0f / prow[k];
      float f = row[k] * pinv;
      if (lane == k) {
        #pragma unroll
        for (int c = 0; c < AUGW; ++c) row[c] *= pinv;
      } else {
        #pragma unroll
        for (int c = 0; c < AUGW; ++c) row[c] -= f * prow[c];
      }
    }
    #pragma unroll
    for (int c = 0; c < NCLS; ++c) S[lane * NCLS + c] = row[NC + c];
  }
}

// ---------------- predictions: orig_pred and y_pred ----------------
__global__ __launch_bounds__(256) void k_pred(const float* __restrict__ X,
                                              const float* __restrict__ C,
                                              const float* __restrict__ W,
                                              const float* __restrict__ bvec,
                                              const float* __restrict__ S,
                                              float* __restrict__ out, int bs) {
  __shared__ float4 Cs4[2048];   // 32 KB: Cs4[d*8+u] = C4[d*8 + (u ^ ((d>>3)&7))]
  __shared__ float2 Ws2[1280];   // 10 KB
  int t = threadIdx.x;
  const float4* C4 = (const float4*)C;
  for (int s = t; s < 2048; s += 256)
    Cs4[s] = C4[(s & ~7) | ((s & 7) ^ ((s >> 6) & 7))];
  const float2* W2 = (const float2*)W;
  for (int s = t; s < 1280; s += 256) Ws2[s] = W2[s];
  __syncthreads();

  int r = blockIdx.x * 8 + (t >> 5);
  int q = t & 31;
  const float4* x4 = reinterpret_cast<const float4*>(X + (size_t)r * D);
  float4 xa = x4[q * 2], xb = x4[q * 2 + 1];

  float a[NC], o[NCLS];
  #pragma unroll
  for (int c = 0; c < NC; ++c) a[c] = 0.f;
  #pragma unroll
  for (int c = 0; c < NCLS; ++c) o[c] = 0.f;

  #pragma unroll
  for (int i = 0; i < 8; ++i) {
    int d = q * 8 + i;
    float xd = (i < 4) ? reinterpret_cast<const float*>(&xa)[i]
                       : reinterpret_cast<const float*>(&xb)[i - 4];
    int sw = (d >> 3) & 7;
    #pragma unroll
    for (int c4 = 0; c4 < 8; ++c4) {
      float4 cv = Cs4[d * 8 + (c4 ^ sw)];
      a[c4 * 4 + 0] += xd * cv.x; a[c4 * 4 + 1] += xd * cv.y;
      a[c4 * 4 + 2] += xd * cv.z; a[c4 * 4 + 3] += xd * cv.w;
    }
    #pragma unroll
    for (int j = 0; j < 5; ++j) {
      float2 wv = Ws2[d * 5 + j];
      o[j * 2 + 0] += xd * wv.x; o[j * 2 + 1] += xd * wv.y;
    }
  }
  #pragma unroll
  for (int off = 1; off < 32; off <<= 1) {
    #pragma unroll
    for (int c = 0; c < NC; ++c) a[c] += __shfl_xor(a[c], off);
    #pragma unroll
    for (int c = 0; c < NCLS; ++c) o[c] += __shfl_xor(o[c], off);
  }
  if (q < NCLS) {
    float b = bvec[q];
    out[(size_t)r * NCLS + q] = o[q] + b;
    float y = b;
    #pragma unroll
    for (int c = 0; c < NC; ++c) y += a[c] * S[c * NCLS + q];
    out[(size_t)bs * NCLS + (size_t)r * NCLS + q] = y;
  }
}

// ---------------- per-(concept, chunk) exact top-10, float4 scan ----------------
__global__ __launch_bounds__(256) void k_topk(const float* __restrict__ keyT,
                                              float* __restrict__ candK,
                                              int* __restrict__ candI, int N) {
  int j = blockIdx.y, blk = blockIdx.x, tid = threadIdx.x;
  const float* key = keyT + (size_t)j * N;
  int per = (((N + NBLK - 1) / NBLK) + 3) & ~3;
  int lo = blk * per;
  int hi = lo + per; if (hi > N) hi = N;

  float bk[KNN]; int bi[KNN];
  #pragma unroll
  for (int q = 0; q < KNN; ++q) { bk[q] = 3.4e38f; bi[q] = 0x7fffffff; }

  if (lo < N) {
    const float4* key4 = reinterpret_cast<const float4*>(key + lo);
    int n4 = (hi - lo) >> 2;
    for (int i4 = tid; i4 < n4; i4 += 256) {
      float4 v4 = key4[i4];
      #pragma unroll
      for (int c = 0; c < 4; ++c) {
        float v = reinterpret_cast<const float*>(&v4)[c];
        int gi = lo + (i4 << 2) + c;
        if (v < bk[KNN - 1] || (v == bk[KNN - 1] && gi < bi[KNN - 1])) {
          float cv = v; int ci = gi;
          #pragma unroll
          for (int q = 0; q < KNN; ++q) {
            bool take = (cv < bk[q]) || (cv == bk[q] && ci < bi[q]);
            if (take) {
              float tf = bk[q]; bk[q] = cv; cv = tf;
              int ti = bi[q]; bi[q] = ci; ci = ti;
            }
          }
        }
      }
    }
    for (int i = lo + (n4 << 2) + tid; i < hi; i += 256) {
      float v = key[i];
      if (v < bk[KNN - 1] || (v == bk[KNN - 1] && i < bi[KNN - 1])) {
        float cv = v; int ci = i;
        #pragma unroll
        for (int q = 0; q < KNN; ++q) {
          bool take = (cv < bk[q]) || (cv == bk[q] && ci < bi[q]);
          if (take) {
            float tf = bk[q]; bk[q] = cv; cv = tf;
            int ti = bi[q]; bi[q] = ci; ci = ti;
          }
        }
      }
    }
  }

  __shared__ float sk[256 * KNN];
  __shared__ int si[256 * KNN];
  __shared__ float wv_[4]; __shared__ int wi_[4];
  #pragma unroll
  for (int q = 0; q < KNN; ++q) { sk[tid * KNN + q] = bk[q]; si[tid * KNN + q] = bi[q]; }
  __syncthreads();

  int p = 0;
  int lane = tid & 63, wv = tid >> 6;
  for (int rr = 0; rr < KNN; ++rr) {
    float myv = (p < KNN) ? sk[tid * KNN + p] : 3.4e38f;
    int mygi = (p < KNN) ? si[tid * KNN + p] : 0x7fffffff;
    float hv = myv; int hgi = mygi;
    #pragma unroll
    for (int off = 32; off; off >>= 1) {
      float ov = __shfl_xor(hv, off); int oi = __shfl_xor(hgi, off);
      if (ov < hv || (ov == hv && oi < hgi)) { hv = ov; hgi = oi; }
    }
    if (lane == 0) { wv_[wv] = hv; wi_[wv] = hgi; }
    __syncthreads();
    float bv = wv_[0]; int bgi = wi_[0];
    #pragma unroll
    for (int w = 1; w < 4; ++w) {
      if (wv_[w] < bv || (wv_[w] == bv && wi_[w] < bgi)) { bv = wv_[w]; bgi = wi_[w]; }
    }
    if (p < KNN && myv == bv && mygi == bgi) p++;
    if (tid == 0) {
      candK[((size_t)j * NBLK + blk) * KNN + rr] = bv;
      candI[((size_t)j * NBLK + blk) * KNN + rr] = bgi;
    }
    __syncthreads();
  }
}

// ---------------- merge candidates, gather knn, dot with concept ----------------
// grid: NC blocks x 256 threads (thread == d in gather phase)
__global__ __launch_bounds__(256) void k_final(const float* __restrict__ candK,
                                               const int* __restrict__ candI,
                                               const float* __restrict__ X,
                                               const float* __restrict__ Cc,
                                               float* __restrict__ dots) {
  int j = blockIdx.x, tid = threadIdx.x;
  const int M = NBLK * KNN; // 320
  __shared__ float mk[M]; __shared__ int mi[M];
  __shared__ int topIdx[KNN];
  __shared__ float wvv[4]; __shared__ int wvi[4]; __shared__ int wvp[4];
  __shared__ float rsum[4];
  for (int e = tid; e < M; e += 256) { mk[e] = candK[(size_t)j * M + e]; mi[e] = candI[(size_t)j * M + e]; }
  __syncthreads();

  int lane = tid & 63, wv = tid >> 6;
  for (int rr = 0; rr < KNN; ++rr) {
    float v = 3.4e38f; int gi = 0x7fffffff; int pos = -1;
    for (int e = tid; e < M; e += 256) {
      if (mk[e] < v || (mk[e] == v && mi[e] < gi)) { v = mk[e]; gi = mi[e]; pos = e; }
    }
    #pragma unroll
    for (int off = 32; off; off >>= 1) {
      float ov = __shfl_xor(v, off); int ogi = __shfl_xor(gi, off); int op = __shfl_xor(pos, off);
      if (ov < v || (ov == v && ogi < gi)) { v = ov; gi = ogi; pos = op; }
    }
    if (lane == 0) { wvv[wv] = v; wvi[wv] = gi; wvp[wv] = pos; }
    __syncthreads();
    float bv = wvv[0]; int bgi = wvi[0]; int bpos = wvp[0];
    #pragma unroll
    for (int w = 1; w < 4; ++w) {
      if (wvv[w] < bv || (wvv[w] == bv && wvi[w] < bgi)) { bv = wvv[w]; bgi = wvi[w]; bpos = wvp[w]; }
    }
    if (tid == 0) { topIdx[rr] = bgi; mk[bpos] = 3.4e38f; }
    __syncthreads();
  }

  float cj = Cc[tid * NC + j];
  float acc = 0.f;
  #pragma unroll
  for (int k = 0; k < KNN; ++k) acc += X[(size_t)topIdx[k] * D + tid] * cj;
  acc = wave_sum(acc);
  if (lane == 0) rsum[wv] = acc;
  __syncthreads();
  if (tid == 0) dots[j] = (rsum[0] + rsum[1] + rsum[2] + rsum[3]) * (1.0f / KNN);
}

// ---------------- final scalar: L_sparse_1 = mean(dots) ----------------
__global__ __launch_bounds__(64) void k_scal(const float* __restrict__ dots,
                                             float* __restrict__ out, int bs) {
  int lane = threadIdx.x;
  float v = (lane < NC) ? dots[lane] : 0.f;
  v = wave_sum(v);
  if (lane == 0) out[(size_t)2 * bs * NCLS] = v / (float)NC;
}

extern "C" void kernel_launch(void* const* d_in, const int* in_sizes, int n_in,
                              void* d_out, int out_size, void* d_ws, size_t ws_size,
                              hipStream_t stream) {
  const float* Xb = (const float*)d_in[0]; // train_embedding [bs][D]
  const float* XN = (const float*)d_in[1]; // train_embeddings [N][D]
  const float* C  = (const float*)d_in[2]; // concept [D][NC]
  const float* W  = (const float*)d_in[3]; // W_hx [D][NCLS]
  const float* bv = (const float*)d_in[4]; // b_hx [NCLS]
  float* out = (float*)d_out;

  int bs = in_sizes[0] / D;   // 4096
  int N  = in_sizes[1] / D;   // 200000

  float* w = (float*)d_ws;
  size_t offKey  = 0;
  size_t offS    = (size_t)NC * N;
  size_t offCK   = offS + NC * NCLS;
  size_t offCI   = offCK + (size_t)NC * NBLK * KNN;
  size_t offDots = offCI + (size_t)NC * NBLK * KNN;

  float* keyT  = w + offKey;
  float* S     = w + offS;
  float* candK = w + offCK;
  int*   candI = (int*)(w + offCI);
  float* dots  = w + offDots;

  k_key<<<dim3((N + 63) / 64), dim3(64), 0, stream>>>(XN, C, keyT, N);
  k_gramsolve<<<dim3(1), dim3(1024), 0, stream>>>(C, W, S, out, bs);
  k_pred<<<dim3(bs / 8), dim3(256), 0, stream>>>(Xb, C, W, bv, S, out, bs);
  k_topk<<<dim3(NBLK, NC), dim3(256), 0, stream>>>(keyT, candK, candI, N);
  k_final<<<dim3(NC), dim3(256), 0, stream>>>(candK, candI, XN, C, dots);
  k_scal<<<dim3(1), dim3(64), 0, stream>>>(dots, out, bs);
}

// Round 9
// 185.602 us; speedup vs baseline: 1.5181x; 1.0684x over previous
//
#include <hip/hip_runtime.h>
#include <cstdint>
#include <cstring>

#define D 256
#define NC 32
#define NCLS 10
#define KNN 10
#define NBLK 32

typedef float f32x16 __attribute__((ext_vector_type(16)));
typedef short short8v __attribute__((ext_vector_type(8)));

__device__ __forceinline__ float wave_sum(float v) {
  #pragma unroll
  for (int off = 32; off; off >>= 1) v += __shfl_xor(v, off);
  return v;
}

__device__ __forceinline__ uint32_t fbits(float x) { return __builtin_bit_cast(uint32_t, x); }
__device__ __forceinline__ float bcast(uint32_t b) { return __builtin_bit_cast(float, b); }

// ---------------- precompute C fragments (bf16 hi/lo) for mfma_32x32x16 ----------------
// B-frag layout: lane l supplies B[k = 8*(l>>5)+i][col = l&31], i=0..7, as bf16 pairs.
// Chi/Clo[kstep*64 + lane] = uint4 of 8 packed bf16.
__global__ __launch_bounds__(64) void k_cfrag(const float* __restrict__ C,
                                              uint4* __restrict__ Chi,
                                              uint4* __restrict__ Clo) {
  int l = threadIdx.x;
  int ks = blockIdx.x;           // 0..15
  int col = l & 31, g = l >> 5;
  uint32_t h[8], lo[8];
  #pragma unroll
  for (int i = 0; i < 8; ++i) {
    int k = ks * 16 + g * 8 + i;
    float x = C[(size_t)k * NC + col];
    uint32_t b = fbits(x);
    uint32_t hb = b & 0xFFFF0000u;
    h[i] = hb >> 16;
    float r = x - bcast(hb);
    lo[i] = fbits(r) >> 16;
  }
  uint4 H = make_uint4((h[1] << 16) | h[0], (h[3] << 16) | h[2],
                       (h[5] << 16) | h[4], (h[7] << 16) | h[6]);
  uint4 L = make_uint4((lo[1] << 16) | lo[0], (lo[3] << 16) | lo[2],
                       (lo[5] << 16) | lo[4], (lo[7] << 16) | lo[6]);
  Chi[ks * 64 + l] = H;
  Clo[ks * 64 + l] = L;
}

// ---------------- key = x2 - 2*xc via bf16x4-split MFMA ----------------
// 1 wave/block, 32 rows/block. A-frag: lane l = row base+(l&31), k-half (l>>5).
// 16 K-steps: 2 x-f4 loads + convert (hi/lo) + 2 frag loads + 4 MFMA.
// D-frag (verified m74/m101): col=lane&31(concept), row=(reg&3)+8*(reg>>2)+4*(lane>>5).
// Epilogue: +1-padded LDS transpose -> coalesced keyT stores.
__global__ __launch_bounds__(64) void k_key(const float* __restrict__ X,
                                            const uint4* __restrict__ Chi,
                                            const uint4* __restrict__ Clo,
                                            float* __restrict__ keyT, int N) {
  int l = threadIdx.x;
  int r32 = l & 31, g = l >> 5;
  int base = blockIdx.x * 32;
  int row = base + r32; if (row >= N) row = N - 1;
  const float* xrow = X + (size_t)row * D + g * 8;

  f32x16 a0, a1, a2, a3;
  #pragma unroll
  for (int i = 0; i < 16; ++i) { a0[i] = 0.f; a1[i] = 0.f; a2[i] = 0.f; a3[i] = 0.f; }
  float x2 = 0.f;

  #pragma unroll 4
  for (int ks = 0; ks < 16; ++ks) {
    float4 xa = *reinterpret_cast<const float4*>(xrow + ks * 16);
    float4 xb = *reinterpret_cast<const float4*>(xrow + ks * 16 + 4);
    float xs[8] = {xa.x, xa.y, xa.z, xa.w, xb.x, xb.y, xb.z, xb.w};
    uint32_t hp[4], lp[4];
    #pragma unroll
    for (int p = 0; p < 4; ++p) {
      float x0 = xs[2 * p], x1 = xs[2 * p + 1];
      x2 = fmaf(x0, x0, x2); x2 = fmaf(x1, x1, x2);
      uint32_t b0 = fbits(x0), b1 = fbits(x1);
      uint32_t h0 = b0 & 0xFFFF0000u, h1 = b1 & 0xFFFF0000u;
      hp[p] = (h1) | (h0 >> 16);
      float r0 = x0 - bcast(h0), r1 = x1 - bcast(h1);
      lp[p] = (fbits(r1) & 0xFFFF0000u) | (fbits(r0) >> 16);
    }
    short8v xh = __builtin_bit_cast(short8v, make_uint4(hp[0], hp[1], hp[2], hp[3]));
    short8v xl = __builtin_bit_cast(short8v, make_uint4(lp[0], lp[1], lp[2], lp[3]));
    short8v bh = __builtin_bit_cast(short8v, Chi[ks * 64 + l]);
    short8v bl = __builtin_bit_cast(short8v, Clo[ks * 64 + l]);
    a0 = __builtin_amdgcn_mfma_f32_32x32x16_bf16(xh, bh, a0, 0, 0, 0);
    a1 = __builtin_amdgcn_mfma_f32_32x32x16_bf16(xh, bl, a1, 0, 0, 0);
    a2 = __builtin_amdgcn_mfma_f32_32x32x16_bf16(xl, bh, a2, 0, 0, 0);
    a3 = __builtin_amdgcn_mfma_f32_32x32x16_bf16(xl, bl, a3, 0, 0, 0);
  }

  x2 += __shfl_xor(x2, 32);         // full-row |x|^2 (lane l holds row l&31's x2)

  __shared__ float kl[32 * 33];
  #pragma unroll
  for (int i = 0; i < 16; ++i) {
    int rr = (i & 3) + 8 * (i >> 2) + 4 * g;          // D row within tile
    kl[rr * 33 + r32] = -2.f * (a0[i] + a1[i] + a2[i] + a3[i]);   // r32 = concept here
  }
  __syncthreads();
  if (base + r32 < N) {
    #pragma unroll
    for (int i = 0; i < 16; ++i) {
      int c = g * 16 + i;
      float v = x2 + kl[r32 * 33 + c];                // r32 = row here
      keyT[(size_t)c * N + base + r32] = v;
    }
  }
}

// ---------------- fused gram + Gauss-Jordan solve + scalar stats ----------------
#define AUGW (NC + NCLS)   // 42
__global__ __launch_bounds__(1024) void k_gramsolve(const float* __restrict__ C,
                                                    const float* __restrict__ W,
                                                    float* __restrict__ S,
                                                    float* __restrict__ out, int bs) {
  __shared__ float Cs[D * NC];     // 32 KB
  __shared__ float Ws[D * NCLS];   // 10 KB
  __shared__ float aug[NC * AUGW];
  int tid = threadIdx.x;
  {
    const float4* C4 = (const float4*)C;  float4* Cs4 = (float4*)Cs;
    Cs4[tid] = C4[tid]; Cs4[tid + 1024] = C4[tid + 1024];
    const float4* W4 = (const float4*)W;  float4* Ws4 = (float4*)Ws;
    if (tid < (D * NCLS) / 4) Ws4[tid] = W4[tid];
  }
  __syncthreads();
  for (int e = tid; e < NC * AUGW; e += 1024) {
    int i = e / AUGW, jj = e % AUGW;
    float acc = 0.f;
    if (jj < NC) {
      for (int d = 0; d < D; ++d) acc += Cs[d * NC + i] * Cs[d * NC + jj];
    } else {
      int cls = jj - NC;
      for (int d = 0; d < D; ++d) acc += Cs[d * NC + i] * Ws[d * NCLS + cls];
    }
    aug[e] = acc;
  }
  __syncthreads();

  if (tid < NC) {
    int lane = tid;
    float row[AUGW];
    #pragma unroll
    for (int c = 0; c < AUGW; ++c) row[c] = aug[lane * AUGW + c];

    float rsum = 0.f;
    #pragma unroll
    for (int c = 0; c < NC; ++c) rsum += row[c];
    float diag = row[lane];
    #pragma unroll
    for (int off = 16; off; off >>= 1) {
      rsum += __shfl_xor(rsum, off);
      diag += __shfl_xor(diag, off);
    }
    if (lane == 0) {
      out[(size_t)2 * bs * NCLS + 1] = (rsum - diag) / (float)(NC * NC); // L_sparse_2
      out[(size_t)2 * bs * NCLS + 2] = diag / (float)(NC * NC);          // norm_metrics
    }

    for (int k = 0; k < NC; ++k) {
      float prow[AUGW];
      #pragma unroll
      for (int c = 0; c < AUGW; ++c) prow[c] = __shfl(row[c], k);
      float pinv = 1.0f / prow[k];
      float f = row[k] * pinv;
      if (lane == k) {
        #pragma unroll
        for (int c = 0; c < AUGW; ++c) row[c] *= pinv;
      } else {
        #pragma unroll
        for (int c = 0; c < AUGW; ++c) row[c] -= f * prow[c];
      }
    }
    #pragma unroll
    for (int c = 0; c < NCLS; ++c) S[lane * NCLS + c] = row[NC + c];
  }
}

// ---------------- predictions: orig_pred and y_pred ----------------
__global__ __launch_bounds__(256) void k_pred(const float* __restrict__ X,
                                              const float* __restrict__ C,
                                              const float* __restrict__ W,
                                              const float* __restrict__ bvec,
                                              const float* __restrict__ S,
                                              float* __restrict__ out, int bs) {
  __shared__ float4 Cs4[2048];   // 32 KB: Cs4[d*8+u] = C4[d*8 + (u ^ ((d>>3)&7))]
  __shared__ float2 Ws2[1280];   // 10 KB
  int t = threadIdx.x;
  const float4* C4 = (const float4*)C;
  for (int s = t; s < 2048; s += 256)
    Cs4[s] = C4[(s & ~7) | ((s & 7) ^ ((s >> 6) & 7))];
  const float2* W2 = (const float2*)W;
  for (int s = t; s < 1280; s += 256) Ws2[s] = W2[s];
  __syncthreads();

  int r = blockIdx.x * 8 + (t >> 5);
  int q = t & 31;
  const float4* x4 = reinterpret_cast<const float4*>(X + (size_t)r * D);
  float4 xa = x4[q * 2], xb = x4[q * 2 + 1];

  float a[NC], o[NCLS];
  #pragma unroll
  for (int c = 0; c < NC; ++c) a[c] = 0.f;
  #pragma unroll
  for (int c = 0; c < NCLS; ++c) o[c] = 0.f;

  #pragma unroll
  for (int i = 0; i < 8; ++i) {
    int d = q * 8 + i;
    float xd = (i < 4) ? reinterpret_cast<const float*>(&xa)[i]
                       : reinterpret_cast<const float*>(&xb)[i - 4];
    int sw = (d >> 3) & 7;
    #pragma unroll
    for (int c4 = 0; c4 < 8; ++c4) {
      float4 cv = Cs4[d * 8 + (c4 ^ sw)];
      a[c4 * 4 + 0] += xd * cv.x; a[c4 * 4 + 1] += xd * cv.y;
      a[c4 * 4 + 2] += xd * cv.z; a[c4 * 4 + 3] += xd * cv.w;
    }
    #pragma unroll
    for (int j = 0; j < 5; ++j) {
      float2 wv = Ws2[d * 5 + j];
      o[j * 2 + 0] += xd * wv.x; o[j * 2 + 1] += xd * wv.y;
    }
  }
  #pragma unroll
  for (int off = 1; off < 32; off <<= 1) {
    #pragma unroll
    for (int c = 0; c < NC; ++c) a[c] += __shfl_xor(a[c], off);
    #pragma unroll
    for (int c = 0; c < NCLS; ++c) o[c] += __shfl_xor(o[c], off);
  }
  if (q < NCLS) {
    float b = bvec[q];
    out[(size_t)r * NCLS + q] = o[q] + b;
    float y = b;
    #pragma unroll
    for (int c = 0; c < NC; ++c) y += a[c] * S[c * NCLS + q];
    out[(size_t)bs * NCLS + (size_t)r * NCLS + q] = y;
  }
}

// ---------------- per-(concept, chunk) exact top-10, float4 scan ----------------
__global__ __launch_bounds__(256) void k_topk(const float* __restrict__ keyT,
                                              float* __restrict__ candK,
                                              int* __restrict__ candI, int N) {
  int j = blockIdx.y, blk = blockIdx.x, tid = threadIdx.x;
  const float* key = keyT + (size_t)j * N;
  int per = (((N + NBLK - 1) / NBLK) + 3) & ~3;
  int lo = blk * per;
  int hi = lo + per; if (hi > N) hi = N;

  float bk[KNN]; int bi[KNN];
  #pragma unroll
  for (int q = 0; q < KNN; ++q) { bk[q] = 3.4e38f; bi[q] = 0x7fffffff; }

  if (lo < N) {
    const float4* key4 = reinterpret_cast<const float4*>(key + lo);
    int n4 = (hi - lo) >> 2;
    for (int i4 = tid; i4 < n4; i4 += 256) {
      float4 v4 = key4[i4];
      #pragma unroll
      for (int c = 0; c < 4; ++c) {
        float v = reinterpret_cast<const float*>(&v4)[c];
        int gi = lo + (i4 << 2) + c;
        if (v < bk[KNN - 1] || (v == bk[KNN - 1] && gi < bi[KNN - 1])) {
          float cv = v; int ci = gi;
          #pragma unroll
          for (int q = 0; q < KNN; ++q) {
            bool take = (cv < bk[q]) || (cv == bk[q] && ci < bi[q]);
            if (take) {
              float tf = bk[q]; bk[q] = cv; cv = tf;
              int ti = bi[q]; bi[q] = ci; ci = ti;
            }
          }
        }
      }
    }
    for (int i = lo + (n4 << 2) + tid; i < hi; i += 256) {
      float v = key[i];
      if (v < bk[KNN - 1] || (v == bk[KNN - 1] && i < bi[KNN - 1])) {
        float cv = v; int ci = i;
        #pragma unroll
        for (int q = 0; q < KNN; ++q) {
          bool take = (cv < bk[q]) || (cv == bk[q] && ci < bi[q]);
          if (take) {
            float tf = bk[q]; bk[q] = cv; cv = tf;
            int ti = bi[q]; bi[q] = ci; ci = ti;
          }
        }
      }
    }
  }

  __shared__ float sk[256 * KNN];
  __shared__ int si[256 * KNN];
  __shared__ float wv_[4]; __shared__ int wi_[4];
  #pragma unroll
  for (int q = 0; q < KNN; ++q) { sk[tid * KNN + q] = bk[q]; si[tid * KNN + q] = bi[q]; }
  __syncthreads();

  int p = 0;
  int lane = tid & 63, wv = tid >> 6;
  for (int rr = 0; rr < KNN; ++rr) {
    float myv = (p < KNN) ? sk[tid * KNN + p] : 3.4e38f;
    int mygi = (p < KNN) ? si[tid * KNN + p] : 0x7fffffff;
    float hv = myv; int hgi = mygi;
    #pragma unroll
    for (int off = 32; off; off >>= 1) {
      float ov = __shfl_xor(hv, off); int oi = __shfl_xor(hgi, off);
      if (ov < hv || (ov == hv && oi < hgi)) { hv = ov; hgi = oi; }
    }
    if (lane == 0) { wv_[wv] = hv; wi_[wv] = hgi; }
    __syncthreads();
    float bv = wv_[0]; int bgi = wi_[0];
    #pragma unroll
    for (int w = 1; w < 4; ++w) {
      if (wv_[w] < bv || (wv_[w] == bv && wi_[w] < bgi)) { bv = wv_[w]; bgi = wi_[w]; }
    }
    if (p < KNN && myv == bv && mygi == bgi) p++;
    if (tid == 0) {
      candK[((size_t)j * NBLK + blk) * KNN + rr] = bv;
      candI[((size_t)j * NBLK + blk) * KNN + rr] = bgi;
    }
    __syncthreads();
  }
}

// ---------------- merge candidates, gather knn, dot with concept ----------------
__global__ __launch_bounds__(256) void k_final(const float* __restrict__ candK,
                                               const int* __restrict__ candI,
                                               const float* __restrict__ X,
                                               const float* __restrict__ Cc,
                                               float* __restrict__ dots) {
  int j = blockIdx.x, tid = threadIdx.x;
  const int M = NBLK * KNN; // 320
  __shared__ float mk[M]; __shared__ int mi[M];
  __shared__ int topIdx[KNN];
  __shared__ float wvv[4]; __shared__ int wvi[4]; __shared__ int wvp[4];
  __shared__ float rsum[4];
  for (int e = tid; e < M; e += 256) { mk[e] = candK[(size_t)j * M + e]; mi[e] = candI[(size_t)j * M + e]; }
  __syncthreads();

  int lane = tid & 63, wv = tid >> 6;
  for (int rr = 0; rr < KNN; ++rr) {
    float v = 3.4e38f; int gi = 0x7fffffff; int pos = -1;
    for (int e = tid; e < M; e += 256) {
      if (mk[e] < v || (mk[e] == v && mi[e] < gi)) { v = mk[e]; gi = mi[e]; pos = e; }
    }
    #pragma unroll
    for (int off = 32; off; off >>= 1) {
      float ov = __shfl_xor(v, off); int ogi = __shfl_xor(gi, off); int op = __shfl_xor(pos, off);
      if (ov < v || (ov == v && ogi < gi)) { v = ov; gi = ogi; pos = op; }
    }
    if (lane == 0) { wvv[wv] = v; wvi[wv] = gi; wvp[wv] = pos; }
    __syncthreads();
    float bv = wvv[0]; int bgi = wvi[0]; int bpos = wvp[0];
    #pragma unroll
    for (int w = 1; w < 4; ++w) {
      if (wvv[w] < bv || (wvv[w] == bv && wvi[w] < bgi)) { bv = wvv[w]; bgi = wvi[w]; bpos = wvp[w]; }
    }
    if (tid == 0) { topIdx[rr] = bgi; mk[bpos] = 3.4e38f; }
    __syncthreads();
  }

  float cj = Cc[tid * NC + j];
  float acc = 0.f;
  #pragma unroll
  for (int k = 0; k < KNN; ++k) acc += X[(size_t)topIdx[k] * D + tid] * cj;
  acc = wave_sum(acc);
  if (lane == 0) rsum[wv] = acc;
  __syncthreads();
  if (tid == 0) dots[j] = (rsum[0] + rsum[1] + rsum[2] + rsum[3]) * (1.0f / KNN);
}

// ---------------- final scalar: L_sparse_1 = mean(dots) ----------------
__global__ __launch_bounds__(64) void k_scal(const float* __restrict__ dots,
                                             float* __restrict__ out, int bs) {
  int lane = threadIdx.x;
  float v = (lane < NC) ? dots[lane] : 0.f;
  v = wave_sum(v);
  if (lane == 0) out[(size_t)2 * bs * NCLS] = v / (float)NC;
}

extern "C" void kernel_launch(void* const* d_in, const int* in_sizes, int n_in,
                              void* d_out, int out_size, void* d_ws, size_t ws_size,
                              hipStream_t stream) {
  const float* Xb = (const float*)d_in[0]; // train_embedding [bs][D]
  const float* XN = (const float*)d_in[1]; // train_embeddings [N][D]
  const float* C  = (const float*)d_in[2]; // concept [D][NC]
  const float* W  = (const float*)d_in[3]; // W_hx [D][NCLS]
  const float* bv = (const float*)d_in[4]; // b_hx [NCLS]
  float* out = (float*)d_out;

  int bs = in_sizes[0] / D;   // 4096
  int N  = in_sizes[1] / D;   // 200000

  float* w = (float*)d_ws;
  size_t offKey  = 0;
  size_t offS    = (size_t)NC * N;
  size_t offCK   = offS + NC * NCLS;
  size_t offCI   = offCK + (size_t)NC * NBLK * KNN;
  size_t offDots = offCI + (size_t)NC * NBLK * KNN;
  size_t offChi  = offDots + 64;               // 16-B aligned (all offsets %4==0)
  size_t offClo  = offChi + 16 * 64 * 4;       // 16 KB of uint4 = 4096 floats

  float* keyT  = w + offKey;
  float* S     = w + offS;
  float* candK = w + offCK;
  int*   candI = (int*)(w + offCI);
  float* dots  = w + offDots;
  uint4* Chi   = (uint4*)(w + offChi);
  uint4* Clo   = (uint4*)(w + offClo);

  k_cfrag<<<dim3(16), dim3(64), 0, stream>>>(C, Chi, Clo);
  k_key<<<dim3((N + 31) / 32), dim3(64), 0, stream>>>(XN, Chi, Clo, keyT, N);
  k_gramsolve<<<dim3(1), dim3(1024), 0, stream>>>(C, W, S, out, bs);
  k_pred<<<dim3(bs / 8), dim3(256), 0, stream>>>(Xb, C, W, bv, S, out, bs);
  k_topk<<<dim3(NBLK, NC), dim3(256), 0, stream>>>(keyT, candK, candI, N);
  k_final<<<dim3(NC), dim3(256), 0, stream>>>(candK, candI, XN, C, dots);
  k_scal<<<dim3(1), dim3(64), 0, stream>>>(dots, out, bs);
}

// Round 10
// 180.669 us; speedup vs baseline: 1.5595x; 1.0273x over previous
//
#include <hip/hip_runtime.h>
#include <cstdint>

#define D 256
#define NC 32
#define NCLS 10
#define KNN 10
#define NBLK 32
#define KROWS 128

typedef float f32x16 __attribute__((ext_vector_type(16)));
typedef short short8v __attribute__((ext_vector_type(8)));
typedef const __attribute__((address_space(1))) unsigned int* gp1_t;
typedef __attribute__((address_space(3))) unsigned int* sp3_t;

__device__ __forceinline__ float wave_sum(float v) {
  #pragma unroll
  for (int off = 32; off; off >>= 1) v += __shfl_xor(v, off);
  return v;
}

__device__ __forceinline__ uint32_t fbits(float x) { return __builtin_bit_cast(uint32_t, x); }
__device__ __forceinline__ float bcast(uint32_t b) { return __builtin_bit_cast(float, b); }

// ---------------- key = x2 - 2*xc via bf16-split MFMA, LDS-staged X ----------------
// 4 waves, 128 rows/block; wave w owns rows w*32..w*32+31 (A-frag: lane row=l&31,
// k-half g=l>>5). X staged coalesced via global_load_lds (full 128B lines), source
// pre-swizzled f4 = m ^ (r&7); compute reads 2x ds_read_b128 per ks (<=4-way).
// 3 MFMAs per ks (hi*hi, hi*lo, lo*hi; lo*lo dropped ~2^-32).
__global__ __launch_bounds__(256, 4) void k_key(const float* __restrict__ X,
                                                const uint4* __restrict__ Chi,
                                                const uint4* __restrict__ Clo,
                                                float* __restrict__ keyT, int N) {
  __shared__ float4 xt[2][1024];   // 2 x 16 KB
  int t = threadIdx.x;
  int lane = t & 63;
  int wvu = __builtin_amdgcn_readfirstlane(t >> 6);   // 0..3
  int r32 = lane & 31, g = lane >> 5;
  int rowbase = blockIdx.x * KROWS;
  int arow = wvu * 32 + r32;                          // A row within 128-tile

  auto stage = [&](int buf, int ch) {
    #pragma unroll
    for (int i = 0; i < 4; ++i) {
      int sbase = i * 256 + wvu * 64;
      int s = sbase + lane;                 // linear LDS f4 slot
      int r = s >> 3, m = s & 7;
      int f4 = m ^ (r & 7);                 // inverse swizzle on SOURCE (rule #21)
      int gr = rowbase + r; if (gr >= N) gr = N - 1;
      const float* src = X + (size_t)gr * D + ch * 32 + f4 * 4;
      __builtin_amdgcn_global_load_lds((gp1_t)(const void*)src,
          (sp3_t)(void*)(&xt[buf][sbase]), 16, 0, 0);
    }
  };

  stage(0, 0);

  f32x16 a0, a1, a2;
  #pragma unroll
  for (int i = 0; i < 16; ++i) { a0[i] = 0.f; a1[i] = 0.f; a2[i] = 0.f; }
  float x2 = 0.f;

  for (int ch = 0; ch < 8; ++ch) {          // 8 chunks x 32 floats
    __syncthreads();                        // staged chunk visible; prev readers done
    int cb = ch & 1;
    if (ch < 7) stage(cb ^ 1, ch + 1);
    #pragma unroll
    for (int kq = 0; kq < 2; ++kq) {        // 2 K-steps per chunk
      int ks = ch * 2 + kq;
      int m0 = kq * 4 + g * 2;
      float4 xa = xt[cb][arow * 8 + (m0 ^ (arow & 7))];
      float4 xb = xt[cb][arow * 8 + ((m0 + 1) ^ (arow & 7))];
      float xs[8] = {xa.x, xa.y, xa.z, xa.w, xb.x, xb.y, xb.z, xb.w};
      uint32_t hp[4], lp[4];
      #pragma unroll
      for (int p = 0; p < 4; ++p) {
        float x0 = xs[2 * p], x1 = xs[2 * p + 1];
        x2 = fmaf(x0, x0, x2); x2 = fmaf(x1, x1, x2);
        uint32_t h0 = fbits(x0) & 0xFFFF0000u, h1 = fbits(x1) & 0xFFFF0000u;
        hp[p] = h1 | (h0 >> 16);
        float r0 = x0 - bcast(h0), r1 = x1 - bcast(h1);
        lp[p] = (fbits(r1) & 0xFFFF0000u) | (fbits(r0) >> 16);
      }
      short8v xh = __builtin_bit_cast(short8v, make_uint4(hp[0], hp[1], hp[2], hp[3]));
      short8v xl = __builtin_bit_cast(short8v, make_uint4(lp[0], lp[1], lp[2], lp[3]));
      short8v bh = __builtin_bit_cast(short8v, Chi[ks * 64 + lane]);
      short8v bl = __builtin_bit_cast(short8v, Clo[ks * 64 + lane]);
      a0 = __builtin_amdgcn_mfma_f32_32x32x16_bf16(xh, bh, a0, 0, 0, 0);
      a1 = __builtin_amdgcn_mfma_f32_32x32x16_bf16(xh, bl, a1, 0, 0, 0);
      a2 = __builtin_amdgcn_mfma_f32_32x32x16_bf16(xl, bh, a2, 0, 0, 0);
    }
  }

  x2 += __shfl_xor(x2, 32);                 // full-row |x|^2 for row r32

  __syncthreads();                          // ALL compute reads of xt done
  float* klp = reinterpret_cast<float*>(xt) + wvu * (32 * 33);   // wave-private
  #pragma unroll
  for (int i = 0; i < 16; ++i) {
    int rr = (i & 3) + 8 * (i >> 2) + 4 * g;          // D row within 32-tile
    klp[rr * 33 + r32] = -2.f * (a0[i] + a1[i] + a2[i]);   // r32 = concept col
  }
  __syncthreads();
  int grow = rowbase + wvu * 32 + r32;
  if (grow < N) {
    #pragma unroll
    for (int i = 0; i < 16; ++i) {
      int c = g * 16 + i;
      keyT[(size_t)c * N + grow] = x2 + klp[r32 * 33 + c];   // r32 = row here
    }
  }
}

// ---------------- fused C-fragments + gram + Gauss-Jordan + scalar stats ----------------
#define AUGW (NC + NCLS)   // 42
__global__ __launch_bounds__(1024) void k_gramsolve(const float* __restrict__ C,
                                                    const float* __restrict__ W,
                                                    uint4* __restrict__ Chi,
                                                    uint4* __restrict__ Clo,
                                                    float* __restrict__ S,
                                                    float* __restrict__ out, int bs) {
  int tid = threadIdx.x;
  // --- phase 0: C bf16 hi/lo fragments (wave ws <-> kstep ws) ---
  {
    int l = tid & 63, ks = tid >> 6;        // ks 0..15
    int col = l & 31, g = l >> 5;
    uint32_t h[8], lo[8];
    #pragma unroll
    for (int i = 0; i < 8; ++i) {
      int k = ks * 16 + g * 8 + i;
      float x = C[(size_t)k * NC + col];
      uint32_t hb = fbits(x) & 0xFFFF0000u;
      h[i] = hb >> 16;
      lo[i] = fbits(x - bcast(hb)) >> 16;
    }
    Chi[ks * 64 + l] = make_uint4((h[1] << 16) | h[0], (h[3] << 16) | h[2],
                                  (h[5] << 16) | h[4], (h[7] << 16) | h[6]);
    Clo[ks * 64 + l] = make_uint4((lo[1] << 16) | lo[0], (lo[3] << 16) | lo[2],
                                  (lo[5] << 16) | lo[4], (lo[7] << 16) | lo[6]);
  }

  __shared__ float Cs[D * NC];     // 32 KB
  __shared__ float Ws[D * NCLS];   // 10 KB
  __shared__ float aug[NC * AUGW];
  {
    const float4* C4 = (const float4*)C;  float4* Cs4 = (float4*)Cs;
    Cs4[tid] = C4[tid]; Cs4[tid + 1024] = C4[tid + 1024];
    const float4* W4 = (const float4*)W;  float4* Ws4 = (float4*)Ws;
    if (tid < (D * NCLS) / 4) Ws4[tid] = W4[tid];
  }
  __syncthreads();
  for (int e = tid; e < NC * AUGW; e += 1024) {
    int i = e / AUGW, jj = e % AUGW;
    float acc = 0.f;
    if (jj < NC) {
      #pragma unroll 8
      for (int d = 0; d < D; ++d) acc += Cs[d * NC + i] * Cs[d * NC + jj];
    } else {
      int cls = jj - NC;
      #pragma unroll 8
      for (int d = 0; d < D; ++d) acc += Cs[d * NC + i] * Ws[d * NCLS + cls];
    }
    aug[e] = acc;
  }
  __syncthreads();

  if (tid < NC) {
    int lane = tid;
    float row[AUGW];
    #pragma unroll
    for (int c = 0; c < AUGW; ++c) row[c] = aug[lane * AUGW + c];

    float rsum = 0.f;
    #pragma unroll
    for (int c = 0; c < NC; ++c) rsum += row[c];
    float diag = row[lane];
    #pragma unroll
    for (int off = 16; off; off >>= 1) {
      rsum += __shfl_xor(rsum, off);
      diag += __shfl_xor(diag, off);
    }
    if (lane == 0) {
      out[(size_t)2 * bs * NCLS + 1] = (rsum - diag) / (float)(NC * NC); // L_sparse_2
      out[(size_t)2 * bs * NCLS + 2] = diag / (float)(NC * NC);          // norm_metrics
    }

    for (int k = 0; k < NC; ++k) {
      float prow[AUGW];
      #pragma unroll
      for (int c = 0; c < AUGW; ++c) prow[c] = __shfl(row[c], k);
      float pinv = 1.0f / prow[k];
      float f = row[k] * pinv;
      if (lane == k) {
        #pragma unroll
        for (int c = 0; c < AUGW; ++c) row[c] *= pinv;
      } else {
        #pragma unroll
        for (int c = 0; c < AUGW; ++c) row[c] -= f * prow[c];
      }
    }
    #pragma unroll
    for (int c = 0; c < NCLS; ++c) S[lane * NCLS + c] = row[NC + c];
  }
}

// ---------------- predictions: orig_pred and y_pred ----------------
__global__ __launch_bounds__(256) void k_pred(const float* __restrict__ X,
                                              const float* __restrict__ C,
                                              const float* __restrict__ W,
                                              const float* __restrict__ bvec,
                                              const float* __restrict__ S,
                                              float* __restrict__ out, int bs) {
  __shared__ float4 Cs4[2048];   // 32 KB: Cs4[d*8+u] = C4[d*8 + (u ^ ((d>>3)&7))]
  __shared__ float2 Ws2[1280];   // 10 KB
  int t = threadIdx.x;
  const float4* C4 = (const float4*)C;
  for (int s = t; s < 2048; s += 256)
    Cs4[s] = C4[(s & ~7) | ((s & 7) ^ ((s >> 6) & 7))];
  const float2* W2 = (const float2*)W;
  for (int s = t; s < 1280; s += 256) Ws2[s] = W2[s];
  __syncthreads();

  int r = blockIdx.x * 8 + (t >> 5);
  int q = t & 31;
  const float4* x4 = reinterpret_cast<const float4*>(X + (size_t)r * D);
  float4 xa = x4[q * 2], xb = x4[q * 2 + 1];

  float a[NC], o[NCLS];
  #pragma unroll
  for (int c = 0; c < NC; ++c) a[c] = 0.f;
  #pragma unroll
  for (int c = 0; c < NCLS; ++c) o[c] = 0.f;

  #pragma unroll
  for (int i = 0; i < 8; ++i) {
    int d = q * 8 + i;
    float xd = (i < 4) ? reinterpret_cast<const float*>(&xa)[i]
                       : reinterpret_cast<const float*>(&xb)[i - 4];
    int sw = (d >> 3) & 7;
    #pragma unroll
    for (int c4 = 0; c4 < 8; ++c4) {
      float4 cv = Cs4[d * 8 + (c4 ^ sw)];
      a[c4 * 4 + 0] += xd * cv.x; a[c4 * 4 + 1] += xd * cv.y;
      a[c4 * 4 + 2] += xd * cv.z; a[c4 * 4 + 3] += xd * cv.w;
    }
    #pragma unroll
    for (int j = 0; j < 5; ++j) {
      float2 wv = Ws2[d * 5 + j];
      o[j * 2 + 0] += xd * wv.x; o[j * 2 + 1] += xd * wv.y;
    }
  }
  #pragma unroll
  for (int off = 1; off < 32; off <<= 1) {
    #pragma unroll
    for (int c = 0; c < NC; ++c) a[c] += __shfl_xor(a[c], off);
    #pragma unroll
    for (int c = 0; c < NCLS; ++c) o[c] += __shfl_xor(o[c], off);
  }
  if (q < NCLS) {
    float b = bvec[q];
    out[(size_t)r * NCLS + q] = o[q] + b;
    float y = b;
    #pragma unroll
    for (int c = 0; c < NC; ++c) y += a[c] * S[c * NCLS + q];
    out[(size_t)bs * NCLS + (size_t)r * NCLS + q] = y;
  }
}

// ---------------- per-(concept, chunk) exact top-10, float4 scan ----------------
__global__ __launch_bounds__(256) void k_topk(const float* __restrict__ keyT,
                                              float* __restrict__ candK,
                                              int* __restrict__ candI, int N) {
  int j = blockIdx.y, blk = blockIdx.x, tid = threadIdx.x;
  const float* key = keyT + (size_t)j * N;
  int per = (((N + NBLK - 1) / NBLK) + 3) & ~3;
  int lo = blk * per;
  int hi = lo + per; if (hi > N) hi = N;

  float bk[KNN]; int bi[KNN];
  #pragma unroll
  for (int q = 0; q < KNN; ++q) { bk[q] = 3.4e38f; bi[q] = 0x7fffffff; }

  if (lo < N) {
    const float4* key4 = reinterpret_cast<const float4*>(key + lo);
    int n4 = (hi - lo) >> 2;
    for (int i4 = tid; i4 < n4; i4 += 256) {
      float4 v4 = key4[i4];
      #pragma unroll
      for (int c = 0; c < 4; ++c) {
        float v = reinterpret_cast<const float*>(&v4)[c];
        int gi = lo + (i4 << 2) + c;
        if (v < bk[KNN - 1] || (v == bk[KNN - 1] && gi < bi[KNN - 1])) {
          float cv = v; int ci = gi;
          #pragma unroll
          for (int q = 0; q < KNN; ++q) {
            bool take = (cv < bk[q]) || (cv == bk[q] && ci < bi[q]);
            if (take) {
              float tf = bk[q]; bk[q] = cv; cv = tf;
              int ti = bi[q]; bi[q] = ci; ci = ti;
            }
          }
        }
      }
    }
    for (int i = lo + (n4 << 2) + tid; i < hi; i += 256) {
      float v = key[i];
      if (v < bk[KNN - 1] || (v == bk[KNN - 1] && i < bi[KNN - 1])) {
        float cv = v; int ci = i;
        #pragma unroll
        for (int q = 0; q < KNN; ++q) {
          bool take = (cv < bk[q]) || (cv == bk[q] && ci < bi[q]);
          if (take) {
            float tf = bk[q]; bk[q] = cv; cv = tf;
            int ti = bi[q]; bi[q] = ci; ci = ti;
          }
        }
      }
    }
  }

  __shared__ float sk[256 * KNN];
  __shared__ int si[256 * KNN];
  __shared__ float wv_[4]; __shared__ int wi_[4];
  #pragma unroll
  for (int q = 0; q < KNN; ++q) { sk[tid * KNN + q] = bk[q]; si[tid * KNN + q] = bi[q]; }
  __syncthreads();

  int p = 0;
  int lane = tid & 63, wv = tid >> 6;
  for (int rr = 0; rr < KNN; ++rr) {
    float myv = (p < KNN) ? sk[tid * KNN + p] : 3.4e38f;
    int mygi = (p < KNN) ? si[tid * KNN + p] : 0x7fffffff;
    float hv = myv; int hgi = mygi;
    #pragma unroll
    for (int off = 32; off; off >>= 1) {
      float ov = __shfl_xor(hv, off); int oi = __shfl_xor(hgi, off);
      if (ov < hv || (ov == hv && oi < hgi)) { hv = ov; hgi = oi; }
    }
    if (lane == 0) { wv_[wv] = hv; wi_[wv] = hgi; }
    __syncthreads();
    float bv = wv_[0]; int bgi = wi_[0];
    #pragma unroll
    for (int w = 1; w < 4; ++w) {
      if (wv_[w] < bv || (wv_[w] == bv && wi_[w] < bgi)) { bv = wv_[w]; bgi = wi_[w]; }
    }
    if (p < KNN && myv == bv && mygi == bgi) p++;
    if (tid == 0) {
      candK[((size_t)j * NBLK + blk) * KNN + rr] = bv;
      candI[((size_t)j * NBLK + blk) * KNN + rr] = bgi;
    }
    __syncthreads();
  }
}

// ---------------- merge candidates, gather knn, dot with concept ----------------
__global__ __launch_bounds__(256) void k_final(const float* __restrict__ candK,
                                               const int* __restrict__ candI,
                                               const float* __restrict__ X,
                                               const float* __restrict__ Cc,
                                               float* __restrict__ dots) {
  int j = blockIdx.x, tid = threadIdx.x;
  const int M = NBLK * KNN; // 320
  __shared__ float mk[M]; __shared__ int mi[M];
  __shared__ int topIdx[KNN];
  __shared__ float wvv[4]; __shared__ int wvi[4]; __shared__ int wvp[4];
  __shared__ float rsum[4];
  for (int e = tid; e < M; e += 256) { mk[e] = candK[(size_t)j * M + e]; mi[e] = candI[(size_t)j * M + e]; }
  __syncthreads();

  int lane = tid & 63, wv = tid >> 6;
  for (int rr = 0; rr < KNN; ++rr) {
    float v = 3.4e38f; int gi = 0x7fffffff; int pos = -1;
    for (int e = tid; e < M; e += 256) {
      if (mk[e] < v || (mk[e] == v && mi[e] < gi)) { v = mk[e]; gi = mi[e]; pos = e; }
    }
    #pragma unroll
    for (int off = 32; off; off >>= 1) {
      float ov = __shfl_xor(v, off); int ogi = __shfl_xor(gi, off); int op = __shfl_xor(pos, off);
      if (ov < v || (ov == v && ogi < gi)) { v = ov; gi = ogi; pos = op; }
    }
    if (lane == 0) { wvv[wv] = v; wvi[wv] = gi; wvp[wv] = pos; }
    __syncthreads();
    float bv = wvv[0]; int bgi = wvi[0]; int bpos = wvp[0];
    #pragma unroll
    for (int w = 1; w < 4; ++w) {
      if (wvv[w] < bv || (wvv[w] == bv && wvi[w] < bgi)) { bv = wvv[w]; bgi = wvi[w]; bpos = wvp[w]; }
    }
    if (tid == 0) { topIdx[rr] = bgi; mk[bpos] = 3.4e38f; }
    __syncthreads();
  }

  float cj = Cc[tid * NC + j];
  float acc = 0.f;
  #pragma unroll
  for (int k = 0; k < KNN; ++k) acc += X[(size_t)topIdx[k] * D + tid] * cj;
  acc = wave_sum(acc);
  if (lane == 0) rsum[wv] = acc;
  __syncthreads();
  if (tid == 0) dots[j] = (rsum[0] + rsum[1] + rsum[2] + rsum[3]) * (1.0f / KNN);
}

// ---------------- final scalar: L_sparse_1 = mean(dots) ----------------
__global__ __launch_bounds__(64) void k_scal(const float* __restrict__ dots,
                                             float* __restrict__ out, int bs) {
  int lane = threadIdx.x;
  float v = (lane < NC) ? dots[lane] : 0.f;
  v = wave_sum(v);
  if (lane == 0) out[(size_t)2 * bs * NCLS] = v / (float)NC;
}

extern "C" void kernel_launch(void* const* d_in, const int* in_sizes, int n_in,
                              void* d_out, int out_size, void* d_ws, size_t ws_size,
                              hipStream_t stream) {
  const float* Xb = (const float*)d_in[0]; // train_embedding [bs][D]
  const float* XN = (const float*)d_in[1]; // train_embeddings [N][D]
  const float* C  = (const float*)d_in[2]; // concept [D][NC]
  const float* W  = (const float*)d_in[3]; // W_hx [D][NCLS]
  const float* bv = (const float*)d_in[4]; // b_hx [NCLS]
  float* out = (float*)d_out;

  int bs = in_sizes[0] / D;   // 4096
  int N  = in_sizes[1] / D;   // 200000

  float* w = (float*)d_ws;
  size_t offKey  = 0;
  size_t offS    = (size_t)NC * N;
  size_t offCK   = offS + NC * NCLS;
  size_t offCI   = offCK + (size_t)NC * NBLK * KNN;
  size_t offDots = offCI + (size_t)NC * NBLK * KNN;
  size_t offChi  = offDots + 64;               // 16-B aligned
  size_t offClo  = offChi + 16 * 64 * 4;

  float* keyT  = w + offKey;
  float* S     = w + offS;
  float* candK = w + offCK;
  int*   candI = (int*)(w + offCI);
  float* dots  = w + offDots;
  uint4* Chi   = (uint4*)(w + offChi);
  uint4* Clo   = (uint4*)(w + offClo);

  k_gramsolve<<<dim3(1), dim3(1024), 0, stream>>>(C, W, Chi, Clo, S, out, bs);
  k_key<<<dim3((N + KROWS - 1) / KROWS), dim3(256), 0, stream>>>(XN, Chi, Clo, keyT, N);
  k_pred<<<dim3(bs / 8), dim3(256), 0, stream>>>(Xb, C, W, bv, S, out, bs);
  k_topk<<<dim3(NBLK, NC), dim3(256), 0, stream>>>(keyT, candK, candI, N);
  k_final<<<dim3(NC), dim3(256), 0, stream>>>(candK, candI, XN, C, dots);
  k_scal<<<dim3(1), dim3(64), 0, stream>>>(dots, out, bs);
}